// Round 1
// 742.910 us; speedup vs baseline: 1.0812x; 1.0812x over previous
//
#include <hip/hip_runtime.h>
#include <hip/hip_bf16.h>
#include <math.h>

#define TT 77
#define MTOT 32768

typedef __attribute__((ext_vector_type(8))) short bf16x8;
typedef __attribute__((ext_vector_type(4))) float floatx4;

#define GPTR(p) ((const __attribute__((address_space(1))) void*)(p))
#define LPTR(p) ((__attribute__((address_space(3))) void*)(p))

__device__ __forceinline__ float wred_sum(float v) {
#pragma unroll
  for (int o = 32; o >= 1; o >>= 1) v += __shfl_xor(v, o, 64);
  return v;
}

__device__ __forceinline__ unsigned short f2bf(float f) {
  unsigned int u = __float_as_uint(f);
  unsigned int r = (u + 0x7fffu + ((u >> 16) & 1u)) >> 16;
  return (unsigned short)r;
}
__device__ __forceinline__ float bf2f(unsigned short h) {
  return __uint_as_float(((unsigned int)h) << 16);
}

// ---------------- LayerNorm over rows of 512 -> bf16 out (one wave per row) ---
__global__ __launch_bounds__(256)
void ln_bf16_kernel(const float* __restrict__ in, const float* __restrict__ gw,
                    const float* __restrict__ gb, unsigned short* __restrict__ out) {
  const int wv = threadIdx.x >> 6, lane = threadIdx.x & 63;
  const size_t row = (size_t)blockIdx.x * 4 + wv;
  const float* p = in + row * 512 + lane * 8;
  float4 a = *(const float4*)p;
  float4 b = *(const float4*)(p + 4);
  float s = a.x + a.y + a.z + a.w + b.x + b.y + b.z + b.w;
  float mu = wred_sum(s) * (1.0f / 512.0f);
  float d[8] = {a.x - mu, a.y - mu, a.z - mu, a.w - mu,
                b.x - mu, b.y - mu, b.z - mu, b.w - mu};
  float ss = 0.f;
#pragma unroll
  for (int i = 0; i < 8; ++i) ss = fmaf(d[i], d[i], ss);
  float var = wred_sum(ss) * (1.0f / 512.0f);
  float rstd = rsqrtf(var + 1e-5f);
  float4 w0 = *(const float4*)(gw + lane * 8);
  float4 w1 = *(const float4*)(gw + lane * 8 + 4);
  float4 c0 = *(const float4*)(gb + lane * 8);
  float4 c1 = *(const float4*)(gb + lane * 8 + 4);
  float o[8];
  o[0] = d[0] * rstd * w0.x + c0.x;  o[1] = d[1] * rstd * w0.y + c0.y;
  o[2] = d[2] * rstd * w0.z + c0.z;  o[3] = d[3] * rstd * w0.w + c0.w;
  o[4] = d[4] * rstd * w1.x + c1.x;  o[5] = d[5] * rstd * w1.y + c1.y;
  o[6] = d[6] * rstd * w1.z + c1.z;  o[7] = d[7] * rstd * w1.w + c1.w;
  __align__(16) unsigned short ob[8];
#pragma unroll
  for (int i = 0; i < 8; ++i) ob[i] = f2bf(o[i]);
  *(uint4*)(out + row * 512 + lane * 8) = *(const uint4*)ob;
}

// ---------------- q row: L2-normalize + fold sim scale + bf16 ------------------
__global__ __launch_bounds__(256)
void qnorm_kernel(const float* __restrict__ q, const float* __restrict__ logit_scale,
                  unsigned short* __restrict__ qnb) {
  const int wv = threadIdx.x >> 6, lane = threadIdx.x & 63;
  const size_t row = (size_t)blockIdx.x * 4 + wv;
  const float ls = fminf(fmaxf(logit_scale[0], -2.0f), 2.0f);
  const float scale = expf(ls) * 0.125f;
  const float* p = q + row * 512 + lane * 8;
  float4 a = *(const float4*)p;
  float4 b = *(const float4*)(p + 4);
  float ss = a.x * a.x + a.y * a.y + a.z * a.z + a.w * a.w +
             b.x * b.x + b.y * b.y + b.z * b.z + b.w * b.w;
  ss = wred_sum(ss);
  const float nsc = scale / fmaxf(sqrtf(ss), 1e-6f);
  float o[8] = {a.x * nsc, a.y * nsc, a.z * nsc, a.w * nsc,
                b.x * nsc, b.y * nsc, b.z * nsc, b.w * nsc};
  __align__(16) unsigned short ob[8];
#pragma unroll
  for (int i = 0; i < 8; ++i) ob[i] = f2bf(o[i]);
  *(uint4*)(qnb + row * 512 + lane * 8) = *(const uint4*)ob;
}

// ---------------- weight transpose + bf16 convert: W[K,N] -> WT[N,K] ----------
__global__ __launch_bounds__(256)
void transpose_bf16_kernel(const float* __restrict__ W, unsigned short* __restrict__ WTb,
                           int K, int N) {
  __shared__ float s[32][33];
  const int tx = threadIdx.x & 31, ty = threadIdx.x >> 5;  // ty 0..7
  const int n0 = blockIdx.x * 32, k0 = blockIdx.y * 32;
#pragma unroll
  for (int j = 0; j < 4; ++j)
    s[ty + 8 * j][tx] = W[(size_t)(k0 + ty + 8 * j) * N + n0 + tx];
  __syncthreads();
#pragma unroll
  for (int j = 0; j < 4; ++j)
    WTb[(size_t)(n0 + ty + 8 * j) * K + k0 + tx] = f2bf(s[tx][ty + 8 * j]);
}

// ---------------- text projections: k (l2-normed, bf16, head-major), v, negmask
__global__ __launch_bounds__(256)
void text_proj_kernel(const float* __restrict__ text,
                      const float* __restrict__ wk, const float* __restrict__ bk,
                      const float* __restrict__ wv, const float* __restrict__ bv,
                      unsigned short* __restrict__ khb,  // [B,8,80,64] bf16
                      float* __restrict__ vf,            // [616,512]
                      float* __restrict__ negm) {        // [8,80]: 0 or -inf
  __shared__ float st[512];
  __shared__ float red[8];
  const int tid = threadIdx.x;
  const int row = blockIdx.x;          // b*77 + t
  const int b = row / 77, t = row - b * 77;
  const int wvid = tid >> 6, lane = tid & 63;
  float t0 = text[(size_t)row * 512 + tid];
  float t1 = text[(size_t)row * 512 + tid + 256];
  st[tid] = t0;
  st[tid + 256] = t1;
  float ab = wred_sum(fabsf(t0) + fabsf(t1));
  if (lane == 0) red[wvid] = ab;
  __syncthreads();
  const int c0 = tid, c1 = tid + 256;
  float ak0 = bk[c0], ak1 = bk[c1];
  float av0 = bv[c0], av1 = bv[c1];
  for (int kk = 0; kk < 512; ++kk) {
    float tv = st[kk];
    ak0 = fmaf(tv, wk[(size_t)kk * 512 + c0], ak0);
    ak1 = fmaf(tv, wk[(size_t)kk * 512 + c1], ak1);
    av0 = fmaf(tv, wv[(size_t)kk * 512 + c0], av0);
    av1 = fmaf(tv, wv[(size_t)kk * 512 + c1], av1);
  }
  float ss = wred_sum(ak0 * ak0 + ak1 * ak1);
  if (lane == 0) red[4 + wvid] = ss;
  __syncthreads();
  float padsum = red[0] + red[1] + red[2] + red[3];
  float sstot = red[4] + red[5] + red[6] + red[7];
  float sc = 1.0f / fmaxf(sqrtf(sstot), 1e-6f);
  const int h0 = c0 >> 6, d0 = c0 & 63;
  const int h1 = c1 >> 6, d1 = c1 & 63;
  khb[(((size_t)b * 8 + h0) * 80 + t) * 64 + d0] = f2bf(ak0 * sc);
  khb[(((size_t)b * 8 + h1) * 80 + t) * 64 + d1] = f2bf(ak1 * sc);
  vf[(size_t)row * 512 + c0] = av0;
  vf[(size_t)row * 512 + c1] = av1;
  if (tid == 0) negm[b * 80 + t] = (padsum <= 1e-6f) ? -INFINITY : 0.0f;
}

// ---------------- zero the k pad rows (t = 77..79) + -inf negmask there -------
__global__ __launch_bounds__(256)
void kpad_zero_kernel(unsigned short* __restrict__ khb, float* __restrict__ negm) {
  // 64 (b,h) * 3 rows * 64 ch = 12288 elements
  const int i = blockIdx.x * 256 + threadIdx.x;
  const int bh = i / 192, rem = i - bh * 192;
  const int t = 77 + rem / 64, d = rem & 63;
  khb[(((size_t)bh) * 80 + t) * 64 + d] = 0;
  if (i < 24) negm[(i / 3) * 80 + 77 + (i % 3)] = -INFINITY;
}

// ---------------- sims via MFMA: SIM[b,h,n,80] = qn . k^T + negmask -----------
__global__ __launch_bounds__(256)
void sim_kernel(const unsigned short* __restrict__ qnb,   // [32768,512] bf16 scaled
                const unsigned short* __restrict__ khb,   // [64,80,64] bf16
                const float* __restrict__ negm,           // [8,80]
                float* __restrict__ SIM) {                // [64,4096,80] fp32
  __shared__ __align__(16) unsigned short As[128 * 72];
  __shared__ __align__(16) unsigned short Bs[80 * 72];
  const int bh = blockIdx.y;           // b*8+h
  const int b = bh >> 3, h = bh & 7;
  const int row0 = blockIdx.x * 128;   // within 4096
  const int tid = threadIdx.x;
  // stage A: 128 rows x 64 bf16 (2 threads per row, 64B each)
  {
    const int r = tid >> 1, half = tid & 1;
    const unsigned short* src = qnb + ((size_t)b * 4096 + row0 + r) * 512 + h * 64 + half * 32;
    unsigned short* dst = As + r * 72 + half * 32;
    *(uint4*)dst = *(const uint4*)src;
    *(uint4*)(dst + 8) = *(const uint4*)(src + 8);
    *(uint4*)(dst + 16) = *(const uint4*)(src + 16);
    *(uint4*)(dst + 24) = *(const uint4*)(src + 24);
  }
  // stage B: 80 rows x 64 bf16
  if (tid < 160) {
    const int r = tid >> 1, half = tid & 1;
    const unsigned short* src = khb + ((size_t)bh * 80 + r) * 64 + half * 32;
    unsigned short* dst = Bs + r * 72 + half * 32;
    *(uint4*)dst = *(const uint4*)src;
    *(uint4*)(dst + 8) = *(const uint4*)(src + 8);
    *(uint4*)(dst + 16) = *(const uint4*)(src + 16);
    *(uint4*)(dst + 24) = *(const uint4*)(src + 24);
  }
  __syncthreads();
  const int w = tid >> 6, lane = tid & 63;
  const int m16 = lane & 15, quad = lane >> 4;
  const unsigned short* aBase = As + (w * 32 + m16) * 72 + quad * 8;
  const unsigned short* bBase = Bs + m16 * 72 + quad * 8;
  bf16x8 af[2][2], bf[5][2];
#pragma unroll
  for (int mi = 0; mi < 2; ++mi)
#pragma unroll
    for (int kk = 0; kk < 2; ++kk)
      af[mi][kk] = *(const bf16x8*)(aBase + mi * 16 * 72 + kk * 32);
#pragma unroll
  for (int ni = 0; ni < 5; ++ni)
#pragma unroll
    for (int kk = 0; kk < 2; ++kk)
      bf[ni][kk] = *(const bf16x8*)(bBase + ni * 16 * 72 + kk * 32);
  const floatx4 zero4 = {0.f, 0.f, 0.f, 0.f};
  floatx4 acc[2][5];
#pragma unroll
  for (int mi = 0; mi < 2; ++mi)
#pragma unroll
    for (int ni = 0; ni < 5; ++ni) acc[mi][ni] = zero4;
#pragma unroll
  for (int kk = 0; kk < 2; ++kk)
#pragma unroll
    for (int mi = 0; mi < 2; ++mi)
#pragma unroll
      for (int ni = 0; ni < 5; ++ni)
        acc[mi][ni] = __builtin_amdgcn_mfma_f32_16x16x32_bf16(af[mi][kk], bf[ni][kk], acc[mi][ni], 0, 0, 0);
  float nm[5];
#pragma unroll
  for (int ni = 0; ni < 5; ++ni) nm[ni] = negm[b * 80 + ni * 16 + m16];
  float* obase = SIM + ((size_t)bh * 4096 + row0 + w * 32 + quad * 4) * 80 + m16;
#pragma unroll
  for (int mi = 0; mi < 2; ++mi)
#pragma unroll
    for (int ni = 0; ni < 5; ++ni)
#pragma unroll
      for (int r = 0; r < 4; ++r)
        obase[(size_t)(mi * 16 + r) * 80 + ni * 16] = acc[mi][ni][r] + nm[ni];
}

// ---------------- lane-per-(row,head) top3 + closed-form softmax/conf + PV ----
// g = b*32768 + n*8 + h : the 8 heads of a row sit in adjacent lanes.
__global__ __launch_bounds__(256)
void attn_topk_pv_kernel(const float* __restrict__ SIM,         // [64,4096,80]
                         const float* __restrict__ vf,          // [616,512]
                         unsigned short* __restrict__ alignedb, // [32768,512] bf16
                         float* __restrict__ conf_out) {        // [32768]
  const int g = blockIdx.x * 256 + threadIdx.x;
  const int b = g >> 15;
  const int local = g & 32767;
  const int n = local >> 3, h = local & 7;
  const float* sp = SIM + ((size_t)(b * 8 + h) * 4096 + n) * 80;

  // ---- streaming top-3 (with argmax) + m4 for boundary-tie detection ----
  float m1 = -INFINITY, m2 = -INFINITY, m3 = -INFINITY, m4 = -INFINITY;
  int a1 = 0, a2 = 0, a3 = 0;
#pragma unroll
  for (int i = 0; i < 20; ++i) {
    const float4 q = ((const float4*)sp)[i];
#pragma unroll
    for (int j = 0; j < 4; ++j) {
      const float v = (j == 0) ? q.x : (j == 1) ? q.y : (j == 2) ? q.z : q.w;
      const int t = i * 4 + j;
      const bool c1 = v > m1, c2 = v > m2, c3 = v > m3, c4 = v > m4;
      m4 = c4 ? (c3 ? m3 : v) : m4;            // uses old m3
      m3 = c3 ? (c2 ? m2 : v) : m3;            // uses old m2
      a3 = c3 ? (c2 ? a2 : t) : a3;
      m2 = c2 ? (c1 ? m1 : v) : m2;            // uses old m1
      a2 = c2 ? (c1 ? a1 : t) : a2;
      m1 = c1 ? v : m1;
      a1 = c1 ? t : a1;
    }
  }

  const bool dead = (m1 == -INFINITY);         // fully-padded row
  if (dead) m1 = 0.0f;
  // any duplicate inside top-3, or a 4th value tied with the threshold
  const bool tie = (!dead) && ((m1 == m2) || (m2 == m3) || (m3 == m4));

  // ---- closed-form softmax pieces (fast path: survivors = {a1,a2,a3}) ----
  const float d2 = m2 - m1, d3 = m3 - m1;      // <= 0 (or -inf)
  const float e2 = expf(d2), e3 = expf(d3);    // exp(-inf) = 0
  float s0 = 1.0f + e2 + e3;
  float s1 = ((e2 > 0.f) ? e2 * d2 : 0.f) + ((e3 > 0.f) ? e3 * d3 : 0.f);
  float cntf = 1.0f + ((e2 > 0.f) ? 1.f : 0.f) + ((e3 > 0.f) ? 1.f : 0.f);

  // ---- PV: 3 dense 64-ch FMAs against L2-resident V ----
  const float w1 = dead ? 0.f : 1.f;
  const float* v1p = vf + (size_t)(b * 77 + a1) * 512 + h * 64;
  const float* v2p = vf + (size_t)(b * 77 + a2) * 512 + h * 64;
  const float* v3p = vf + (size_t)(b * 77 + a3) * 512 + h * 64;
  float4 acc[16];
#pragma unroll
  for (int i = 0; i < 16; ++i) {
    const float4 x1 = ((const float4*)v1p)[i];
    const float4 x2 = ((const float4*)v2p)[i];
    const float4 x3 = ((const float4*)v3p)[i];
    float4 r;
    r.x = fmaf(e3, x3.x, fmaf(e2, x2.x, w1 * x1.x));
    r.y = fmaf(e3, x3.y, fmaf(e2, x2.y, w1 * x1.y));
    r.z = fmaf(e3, x3.z, fmaf(e2, x2.z, w1 * x1.z));
    r.w = fmaf(e3, x3.w, fmaf(e2, x2.w, w1 * x1.w));
    acc[i] = r;
  }

  // ---- exact-tie slow path (never taken on continuous data) ----
  if (__any(tie)) {
    if (tie) {
      s0 = 0.f; s1 = 0.f; cntf = 0.f;
#pragma unroll
      for (int i = 0; i < 16; ++i) acc[i] = (float4){0.f, 0.f, 0.f, 0.f};
      for (int t = 0; t < 80; ++t) {
        const float v = sp[t];
        if (v >= m3) {
          const float e = expf(v - m1);
          if (e > 0.f) {
            s0 += e; s1 = fmaf(e, v - m1, s1); cntf += 1.f;
            const float4* vp = (const float4*)(vf + (size_t)(b * 77 + t) * 512 + h * 64);
#pragma unroll
            for (int i = 0; i < 16; ++i) {
              const float4 x = vp[i];
              acc[i].x = fmaf(e, x.x, acc[i].x);
              acc[i].y = fmaf(e, x.y, acc[i].y);
              acc[i].z = fmaf(e, x.z, acc[i].z);
              acc[i].w = fmaf(e, x.w, acc[i].w);
            }
          }
        }
      }
    }
  }

  // ---- conf from closed form: -sum p log p = log(s0) - s1/s0 ----
  const float inv = 1.0f / s0;
  const float entn = (logf(s0) - s1 * inv) + (77.0f - cntf) * 1.8420681e-7f;
  const float ent = fmaxf(entn / logf(fmaxf(cntf, 2.0f)), 0.0f);
  float conf_h = fminf(fmaxf(inv * (1.0f - ent), 0.0f), 1.0f);
  if (dead) conf_h = 0.f;
  float cs = conf_h;
  cs += __shfl_xor(cs, 1, 64);
  cs += __shfl_xor(cs, 2, 64);
  cs += __shfl_xor(cs, 4, 64);
  if (h == 0) {
    const float cm = fminf(fmaxf(cs * 0.125f, 0.0f), 1.0f);
    conf_out[(size_t)b * 4096 + n] = 0.35f + 0.65f * cm;
  }

  // ---- store aligned (bf16, 128B contiguous per lane) ----
  unsigned short* op = alignedb + ((size_t)b * 4096 + n) * 512 + h * 64;
#pragma unroll
  for (int i = 0; i < 8; ++i) {
    const float4 lo = acc[2 * i], hi = acc[2 * i + 1];
    uint4 pk;
    pk.x = (unsigned int)f2bf(lo.x * inv) | ((unsigned int)f2bf(lo.y * inv) << 16);
    pk.y = (unsigned int)f2bf(lo.z * inv) | ((unsigned int)f2bf(lo.w * inv) << 16);
    pk.z = (unsigned int)f2bf(hi.x * inv) | ((unsigned int)f2bf(hi.y * inv) << 16);
    pk.w = (unsigned int)f2bf(hi.z * inv) | ((unsigned int)f2bf(hi.w * inv) << 16);
    *(uint4*)(op + i * 8) = pk;
  }
}

// ---------------- bf16 MFMA GEMM: out = epi(A[M,K] @ WT[N,K]^T + bias) --------
template <int EPI>
__global__ __launch_bounds__(256)
void mfma_gemm(const unsigned short* __restrict__ A,
               const unsigned short* __restrict__ WT,
               const float* __restrict__ bias,
               void* __restrict__ outv, int M, int N, int K,
               const unsigned short* __restrict__ e0b,
               const float* __restrict__ e1f,
               const float* __restrict__ e2f,
               const float* __restrict__ scf) {
  __shared__ __align__(16) unsigned short As[128 * 32];
  __shared__ __align__(16) unsigned short Bs[128 * 32];
  const int tid = threadIdx.x;
  const int wid = tid >> 6, lane = tid & 63;
  const int wr = wid >> 1, wc = wid & 1;
  const int m16 = lane & 15, quad = lane >> 4;
  const int row0 = blockIdx.y * 128, col0 = blockIdx.x * 128;

  const floatx4 zero4 = {0.f, 0.f, 0.f, 0.f};
  floatx4 acc[4][4];
#pragma unroll
  for (int i = 0; i < 4; ++i)
#pragma unroll
    for (int j = 0; j < 4; ++j) acc[i][j] = zero4;

  const unsigned short* Ag = A + (size_t)(row0 + (tid >> 2)) * K + (tid & 3) * 8;
  const unsigned short* Bg = WT + (size_t)(col0 + (tid >> 2)) * K + (tid & 3) * 8;
  char* AsB = (char*)As + tid * 16;
  char* BsB = (char*)Bs + tid * 16;
  const unsigned short* aP = As + (wr * 64 + m16) * 32 + quad * 8;
  const unsigned short* bP = Bs + (wc * 64 + m16) * 32 + quad * 8;

  for (int k0 = 0; k0 < K; k0 += 32) {
    __syncthreads();
    __builtin_amdgcn_global_load_lds(GPTR(Ag + k0), LPTR(AsB), 16, 0, 0);
    __builtin_amdgcn_global_load_lds(GPTR(Ag + (size_t)64 * K + k0), LPTR(AsB + 4096), 16, 0, 0);
    __builtin_amdgcn_global_load_lds(GPTR(Bg + k0), LPTR(BsB), 16, 0, 0);
    __builtin_amdgcn_global_load_lds(GPTR(Bg + (size_t)64 * K + k0), LPTR(BsB + 4096), 16, 0, 0);
    __syncthreads();
    bf16x8 af[4], bfr[4];
#pragma unroll
    for (int i = 0; i < 4; ++i) {
      af[i] = *(const bf16x8*)(aP + i * 16 * 32);
      bfr[i] = *(const bf16x8*)(bP + i * 16 * 32);
    }
#pragma unroll
    for (int mi = 0; mi < 4; ++mi)
#pragma unroll
      for (int ni = 0; ni < 4; ++ni)
        acc[mi][ni] = __builtin_amdgcn_mfma_f32_16x16x32_bf16(af[mi], bfr[ni], acc[mi][ni], 0, 0, 0);
  }

  float* outf = (float*)outv;
  unsigned short* outb = (unsigned short*)outv;
  float bb[4];
#pragma unroll
  for (int ni = 0; ni < 4; ++ni) bb[ni] = bias[col0 + wc * 64 + ni * 16 + m16];
  const float alphav = (EPI == 2) ? scf[0] : 0.f;

#pragma unroll
  for (int mi = 0; mi < 4; ++mi) {
#pragma unroll
    for (int r = 0; r < 4; ++r) {
      const int row = row0 + wr * 64 + mi * 16 + quad * 4 + r;
      float rowscale = 1.f, geo = 0.f;
      if (EPI == 1) rowscale = e1f[row];
      if (EPI == 2) geo = fminf(fmaxf(e2f[row], 0.3f), 1.0f);
#pragma unroll
      for (int ni = 0; ni < 4; ++ni) {
        const int col = col0 + wc * 64 + ni * 16 + m16;
        const size_t idx = (size_t)row * N + col;
        float o = acc[mi][ni][r] + bb[ni];
        if (EPI == 0) {
          outf[idx] = o;
        } else if (EPI == 1) {
          outf[idx] = o * rowscale;
        } else if (EPI == 2) {
          const float x = bf2f(e0b[idx]);
          const float al = e1f[idx];
          const float sg = 1.0f / (1.0f + expf(-o));
          outf[idx] = x + alphav * sg * geo * al;
        } else if (EPI == 3) {
          const float g = 0.5f * o * (1.0f + erff(o * 0.70710678118654752f));
          outb[idx] = f2bf(g);
        } else {
          outf[idx] = o + e1f[idx];
        }
      }
    }
  }
}

extern "C" void kernel_launch(void* const* d_in, const int* in_sizes, int n_in,
                              void* d_out, int out_size, void* d_ws, size_t ws_size,
                              hipStream_t stream) {
  const float* visual = (const float*)d_in[0];
  const float* text   = (const float*)d_in[1];
  const float* geo    = (const float*)d_in[2];
  const float* ln1_w  = (const float*)d_in[3];
  const float* ln1_b  = (const float*)d_in[4];
  const float* wq     = (const float*)d_in[5];
  const float* bq     = (const float*)d_in[6];
  const float* wk     = (const float*)d_in[7];
  const float* bk     = (const float*)d_in[8];
  const float* wvw    = (const float*)d_in[9];
  const float* bv     = (const float*)d_in[10];
  const float* wo     = (const float*)d_in[11];
  const float* bo     = (const float*)d_in[12];
  const float* gate_w = (const float*)d_in[13];
  const float* gate_b = (const float*)d_in[14];
  const float* logit_scale = (const float*)d_in[15];
  const float* alpha  = (const float*)d_in[16];
  const float* ln2_w  = (const float*)d_in[17];
  const float* ln2_b  = (const float*)d_in[18];
  const float* ffn_w1 = (const float*)d_in[19];
  const float* ffn_b1 = (const float*)d_in[20];
  const float* ffn_w2 = (const float*)d_in[21];
  const float* ffn_b2 = (const float*)d_in[22];
  float* out = (float*)d_out;

  char* ws = (char*)d_ws;
  // R0 (88 MB): q fp32 -> SIM fp32 -> alignedO fp32 -> GCH bf16
  float* R0            = (float*)ws;
  float* BUF2          = (float*)(ws + 88080384);             // y fp32, 64 MB
  unsigned short* Xb   = (unsigned short*)(ws + 155189248);   // 32 MB
  unsigned short* QNb  = (unsigned short*)(ws + 188743680);   // 32 MB (-> ALb later)
  unsigned short* wqT  = (unsigned short*)(ws + 222298112);
  unsigned short* woT  = wqT + 262144;
  unsigned short* gateT = woT + 262144;
  unsigned short* w1T  = gateT + 262144;                      // [2048,512]
  unsigned short* w2T  = w1T + 1048576;                       // [512,2048]
  unsigned short* KHb  = w2T + 1048576;                       // [64,80,64] bf16
  float* VF   = (float*)(ws + 228884480);                     // [616,512]
  float* NEGM = (float*)(ws + 230146048);                     // [8,80]
  float* CONF = (float*)(ws + 230148608);                     // [32768]

  float* Qf = R0;
  float* SIM = R0;
  float* AO = R0;
  unsigned short* ALb = QNb;   // aliased: QN dead after sim_kernel

  // weight transposes -> bf16 [N,K]
  transpose_bf16_kernel<<<dim3(16, 16), 256, 0, stream>>>(wq, wqT, 512, 512);
  transpose_bf16_kernel<<<dim3(16, 16), 256, 0, stream>>>(wo, woT, 512, 512);
  transpose_bf16_kernel<<<dim3(16, 16), 256, 0, stream>>>(gate_w, gateT, 512, 512);
  transpose_bf16_kernel<<<dim3(64, 16), 256, 0, stream>>>(ffn_w1, w1T, 512, 2048);
  transpose_bf16_kernel<<<dim3(16, 64), 256, 0, stream>>>(ffn_w2, w2T, 2048, 512);

  // 1. x = LN1(visual) -> bf16
  ln_bf16_kernel<<<MTOT / 4, 256, 0, stream>>>(visual, ln1_w, ln1_b, Xb);
  // 2. text projections (k bf16 head-major [.,80,64], negmask per (b,t))
  text_proj_kernel<<<8 * TT, 256, 0, stream>>>(text, wk, bk, wvw, bv, KHb, VF, NEGM);
  kpad_zero_kernel<<<48, 256, 0, stream>>>(KHb, NEGM);
  // 3. q = x @ wq + bq (fp32)
  mfma_gemm<0><<<dim3(4, 256), 256, 0, stream>>>(Xb, wqT, bq, Qf, MTOT, 512, 512,
                                                 nullptr, nullptr, nullptr, nullptr);
  // 4. qn = l2norm(q) * scale -> bf16
  qnorm_kernel<<<MTOT / 4, 256, 0, stream>>>(Qf, logit_scale, QNb);
  // 5. SIM = qn . k^T + negmask  (MFMA)   [overwrites Qf - dead]
  sim_kernel<<<dim3(32, 64), 256, 0, stream>>>(QNb, KHb, NEGM, SIM);
  // 6. lane-per-(row,head) topk/softmax/conf/PV -> ALb (bf16, overlays QNb), CONF
  attn_topk_pv_kernel<<<1024, 256, 0, stream>>>(SIM, VF, ALb, CONF);
  // 7. alignedO = (aligned @ wo + bo) * conf -> AO fp32 (overlays SIM - dead)
  mfma_gemm<1><<<dim3(4, 256), 256, 0, stream>>>(ALb, woT, bo, AO, MTOT, 512, 512,
                                                 nullptr, CONF, nullptr, nullptr);
  // 8. y = x + alpha*sigmoid(x@gate_w+gate_b)*geo*alignedO -> BUF2
  mfma_gemm<2><<<dim3(4, 256), 256, 0, stream>>>(Xb, gateT, gate_b, BUF2, MTOT, 512, 512,
                                                 Xb, AO, geo, alpha);
  // 9. h = LN2(y) -> Xb (bf16)
  ln_bf16_kernel<<<MTOT / 4, 256, 0, stream>>>(BUF2, ln2_w, ln2_b, Xb);
  // 10. FFN in 2 chunks of 16384 rows; GCH (bf16) overlays R0 (AO dead)
  unsigned short* GCH = (unsigned short*)R0;
  for (int ch = 0; ch < 2; ++ch) {
    const size_t off = (size_t)ch * 16384;
    mfma_gemm<3><<<dim3(16, 128), 256, 0, stream>>>(Xb + off * 512, w1T, ffn_b1, GCH,
                                                    16384, 2048, 512,
                                                    nullptr, nullptr, nullptr, nullptr);
    mfma_gemm<4><<<dim3(4, 128), 256, 0, stream>>>(GCH, w2T, ffn_b2, out + off * 512,
                                                   16384, 512, 2048,
                                                   nullptr, BUF2 + off * 512, nullptr, nullptr);
  }
}

// Round 2
// 705.824 us; speedup vs baseline: 1.1380x; 1.0525x over previous
//
#include <hip/hip_runtime.h>
#include <hip/hip_bf16.h>
#include <math.h>

#define TT 77
#define MTOT 32768

typedef __attribute__((ext_vector_type(8))) short bf16x8;
typedef __attribute__((ext_vector_type(4))) float floatx4;

#define GPTR(p) ((const __attribute__((address_space(1))) void*)(p))
#define LPTR(p) ((__attribute__((address_space(3))) void*)(p))

__device__ __forceinline__ float wred_sum(float v) {
#pragma unroll
  for (int o = 32; o >= 1; o >>= 1) v += __shfl_xor(v, o, 64);
  return v;
}

__device__ __forceinline__ unsigned short f2bf(float f) {
  unsigned int u = __float_as_uint(f);
  unsigned int r = (u + 0x7fffu + ((u >> 16) & 1u)) >> 16;
  return (unsigned short)r;
}
__device__ __forceinline__ float bf2f(unsigned short h) {
  return __uint_as_float(((unsigned int)h) << 16);
}

// fast erf-based GELU: Abramowitz-Stegun 7.1.26, |err| <= 1.5e-7 (way below bf16 lsb)
__device__ __forceinline__ float fast_gelu(float o) {
  const float z = fabsf(o) * 0.70710678118654752f;
  const float t = __builtin_amdgcn_rcpf(fmaf(0.3275911f, z, 1.0f));
  float p = fmaf(1.061405429f, t, -1.453152027f);
  p = fmaf(p, t, 1.421413741f);
  p = fmaf(p, t, -0.284496736f);
  p = fmaf(p, t, 0.254829592f);
  p = p * t;
  const float erfz = fmaf(-p, __expf(-z * z), 1.0f);   // erf(|o|/sqrt2)
  const float s = __builtin_copysignf(erfz, o);
  return 0.5f * o * (1.0f + s);
}

__device__ __forceinline__ float fast_sigmoid(float o) {
  return __builtin_amdgcn_rcpf(1.0f + __expf(-o));
}

// ---------------- LayerNorm over rows of 512 -> bf16 out (one wave per row) ---
__global__ __launch_bounds__(256)
void ln_bf16_kernel(const float* __restrict__ in, const float* __restrict__ gw,
                    const float* __restrict__ gb, unsigned short* __restrict__ out) {
  const int wv = threadIdx.x >> 6, lane = threadIdx.x & 63;
  const size_t row = (size_t)blockIdx.x * 4 + wv;
  const float* p = in + row * 512 + lane * 8;
  float4 a = *(const float4*)p;
  float4 b = *(const float4*)(p + 4);
  float s = a.x + a.y + a.z + a.w + b.x + b.y + b.z + b.w;
  float mu = wred_sum(s) * (1.0f / 512.0f);
  float d[8] = {a.x - mu, a.y - mu, a.z - mu, a.w - mu,
                b.x - mu, b.y - mu, b.z - mu, b.w - mu};
  float ss = 0.f;
#pragma unroll
  for (int i = 0; i < 8; ++i) ss = fmaf(d[i], d[i], ss);
  float var = wred_sum(ss) * (1.0f / 512.0f);
  float rstd = rsqrtf(var + 1e-5f);
  float4 w0 = *(const float4*)(gw + lane * 8);
  float4 w1 = *(const float4*)(gw + lane * 8 + 4);
  float4 c0 = *(const float4*)(gb + lane * 8);
  float4 c1 = *(const float4*)(gb + lane * 8 + 4);
  float o[8];
  o[0] = d[0] * rstd * w0.x + c0.x;  o[1] = d[1] * rstd * w0.y + c0.y;
  o[2] = d[2] * rstd * w0.z + c0.z;  o[3] = d[3] * rstd * w0.w + c0.w;
  o[4] = d[4] * rstd * w1.x + c1.x;  o[5] = d[5] * rstd * w1.y + c1.y;
  o[6] = d[6] * rstd * w1.z + c1.z;  o[7] = d[7] * rstd * w1.w + c1.w;
  __align__(16) unsigned short ob[8];
#pragma unroll
  for (int i = 0; i < 8; ++i) ob[i] = f2bf(o[i]);
  *(uint4*)(out + row * 512 + lane * 8) = *(const uint4*)ob;
}

// ---------------- q row: L2-normalize + fold sim scale + bf16 ------------------
__global__ __launch_bounds__(256)
void qnorm_kernel(const float* __restrict__ q, const float* __restrict__ logit_scale,
                  unsigned short* __restrict__ qnb) {
  const int wv = threadIdx.x >> 6, lane = threadIdx.x & 63;
  const size_t row = (size_t)blockIdx.x * 4 + wv;
  const float ls = fminf(fmaxf(logit_scale[0], -2.0f), 2.0f);
  const float scale = expf(ls) * 0.125f;
  const float* p = q + row * 512 + lane * 8;
  float4 a = *(const float4*)p;
  float4 b = *(const float4*)(p + 4);
  float ss = a.x * a.x + a.y * a.y + a.z * a.z + a.w * a.w +
             b.x * b.x + b.y * b.y + b.z * b.z + b.w * b.w;
  ss = wred_sum(ss);
  const float nsc = scale / fmaxf(sqrtf(ss), 1e-6f);
  float o[8] = {a.x * nsc, a.y * nsc, a.z * nsc, a.w * nsc,
                b.x * nsc, b.y * nsc, b.z * nsc, b.w * nsc};
  __align__(16) unsigned short ob[8];
#pragma unroll
  for (int i = 0; i < 8; ++i) ob[i] = f2bf(o[i]);
  *(uint4*)(qnb + row * 512 + lane * 8) = *(const uint4*)ob;
}

// ---------------- weight transpose + bf16 convert: W[K,N] -> WT[N,K] ----------
__global__ __launch_bounds__(256)
void transpose_bf16_kernel(const float* __restrict__ W, unsigned short* __restrict__ WTb,
                           int K, int N) {
  __shared__ float s[32][33];
  const int tx = threadIdx.x & 31, ty = threadIdx.x >> 5;  // ty 0..7
  const int n0 = blockIdx.x * 32, k0 = blockIdx.y * 32;
#pragma unroll
  for (int j = 0; j < 4; ++j)
    s[ty + 8 * j][tx] = W[(size_t)(k0 + ty + 8 * j) * N + n0 + tx];
  __syncthreads();
#pragma unroll
  for (int j = 0; j < 4; ++j)
    WTb[(size_t)(n0 + ty + 8 * j) * K + k0 + tx] = f2bf(s[tx][ty + 8 * j]);
}

// ---------------- text projections: k (l2-normed, bf16, head-major), v, negmask
__global__ __launch_bounds__(256)
void text_proj_kernel(const float* __restrict__ text,
                      const float* __restrict__ wk, const float* __restrict__ bk,
                      const float* __restrict__ wv, const float* __restrict__ bv,
                      unsigned short* __restrict__ khb,  // [B,8,80,64] bf16
                      float* __restrict__ vf,            // [616,512]
                      float* __restrict__ negm) {        // [8,80]: 0 or -inf
  __shared__ float st[512];
  __shared__ float red[8];
  const int tid = threadIdx.x;
  const int row = blockIdx.x;          // b*77 + t
  const int b = row / 77, t = row - b * 77;
  const int wvid = tid >> 6, lane = tid & 63;
  float t0 = text[(size_t)row * 512 + tid];
  float t1 = text[(size_t)row * 512 + tid + 256];
  st[tid] = t0;
  st[tid + 256] = t1;
  float ab = wred_sum(fabsf(t0) + fabsf(t1));
  if (lane == 0) red[wvid] = ab;
  __syncthreads();
  const int c0 = tid, c1 = tid + 256;
  float ak0 = bk[c0], ak1 = bk[c1];
  float av0 = bv[c0], av1 = bv[c1];
  for (int kk = 0; kk < 512; ++kk) {
    float tv = st[kk];
    ak0 = fmaf(tv, wk[(size_t)kk * 512 + c0], ak0);
    ak1 = fmaf(tv, wk[(size_t)kk * 512 + c1], ak1);
    av0 = fmaf(tv, wv[(size_t)kk * 512 + c0], av0);
    av1 = fmaf(tv, wv[(size_t)kk * 512 + c1], av1);
  }
  float ss = wred_sum(ak0 * ak0 + ak1 * ak1);
  if (lane == 0) red[4 + wvid] = ss;
  __syncthreads();
  float padsum = red[0] + red[1] + red[2] + red[3];
  float sstot = red[4] + red[5] + red[6] + red[7];
  float sc = 1.0f / fmaxf(sqrtf(sstot), 1e-6f);
  const int h0 = c0 >> 6, d0 = c0 & 63;
  const int h1 = c1 >> 6, d1 = c1 & 63;
  khb[(((size_t)b * 8 + h0) * 80 + t) * 64 + d0] = f2bf(ak0 * sc);
  khb[(((size_t)b * 8 + h1) * 80 + t) * 64 + d1] = f2bf(ak1 * sc);
  vf[(size_t)row * 512 + c0] = av0;
  vf[(size_t)row * 512 + c1] = av1;
  if (tid == 0) negm[b * 80 + t] = (padsum <= 1e-6f) ? -INFINITY : 0.0f;
}

// ---------------- zero the k pad rows (t = 77..79) + -inf negmask there -------
__global__ __launch_bounds__(256)
void kpad_zero_kernel(unsigned short* __restrict__ khb, float* __restrict__ negm) {
  // 64 (b,h) * 3 rows * 64 ch = 12288 elements
  const int i = blockIdx.x * 256 + threadIdx.x;
  const int bh = i / 192, rem = i - bh * 192;
  const int t = 77 + rem / 64, d = rem & 63;
  khb[(((size_t)bh) * 80 + t) * 64 + d] = 0;
  if (i < 24) negm[(i / 3) * 80 + 77 + (i % 3)] = -INFINITY;
}

// ---------------- sims via MFMA: SIM[b,h,n,80] = qn . k^T + negmask -----------
__global__ __launch_bounds__(256)
void sim_kernel(const unsigned short* __restrict__ qnb,   // [32768,512] bf16 scaled
                const unsigned short* __restrict__ khb,   // [64,80,64] bf16
                const float* __restrict__ negm,           // [8,80]
                float* __restrict__ SIM) {                // [64,4096,80] fp32
  __shared__ __align__(16) unsigned short As[128 * 72];
  __shared__ __align__(16) unsigned short Bs[80 * 72];
  const int bh = blockIdx.y;           // b*8+h
  const int b = bh >> 3, h = bh & 7;
  const int row0 = blockIdx.x * 128;   // within 4096
  const int tid = threadIdx.x;
  // stage A: 128 rows x 64 bf16 (2 threads per row, 64B each)
  {
    const int r = tid >> 1, half = tid & 1;
    const unsigned short* src = qnb + ((size_t)b * 4096 + row0 + r) * 512 + h * 64 + half * 32;
    unsigned short* dst = As + r * 72 + half * 32;
    *(uint4*)dst = *(const uint4*)src;
    *(uint4*)(dst + 8) = *(const uint4*)(src + 8);
    *(uint4*)(dst + 16) = *(const uint4*)(src + 16);
    *(uint4*)(dst + 24) = *(const uint4*)(src + 24);
  }
  // stage B: 80 rows x 64 bf16
  if (tid < 160) {
    const int r = tid >> 1, half = tid & 1;
    const unsigned short* src = khb + ((size_t)bh * 80 + r) * 64 + half * 32;
    unsigned short* dst = Bs + r * 72 + half * 32;
    *(uint4*)dst = *(const uint4*)src;
    *(uint4*)(dst + 8) = *(const uint4*)(src + 8);
    *(uint4*)(dst + 16) = *(const uint4*)(src + 16);
    *(uint4*)(dst + 24) = *(const uint4*)(src + 24);
  }
  __syncthreads();
  const int w = tid >> 6, lane = tid & 63;
  const int m16 = lane & 15, quad = lane >> 4;
  const unsigned short* aBase = As + (w * 32 + m16) * 72 + quad * 8;
  const unsigned short* bBase = Bs + m16 * 72 + quad * 8;
  bf16x8 af[2][2], bf[5][2];
#pragma unroll
  for (int mi = 0; mi < 2; ++mi)
#pragma unroll
    for (int kk = 0; kk < 2; ++kk)
      af[mi][kk] = *(const bf16x8*)(aBase + mi * 16 * 72 + kk * 32);
#pragma unroll
  for (int ni = 0; ni < 5; ++ni)
#pragma unroll
    for (int kk = 0; kk < 2; ++kk)
      bf[ni][kk] = *(const bf16x8*)(bBase + ni * 16 * 72 + kk * 32);
  const floatx4 zero4 = {0.f, 0.f, 0.f, 0.f};
  floatx4 acc[2][5];
#pragma unroll
  for (int mi = 0; mi < 2; ++mi)
#pragma unroll
    for (int ni = 0; ni < 5; ++ni) acc[mi][ni] = zero4;
#pragma unroll
  for (int kk = 0; kk < 2; ++kk)
#pragma unroll
    for (int mi = 0; mi < 2; ++mi)
#pragma unroll
      for (int ni = 0; ni < 5; ++ni)
        acc[mi][ni] = __builtin_amdgcn_mfma_f32_16x16x32_bf16(af[mi][kk], bf[ni][kk], acc[mi][ni], 0, 0, 0);
  float nm[5];
#pragma unroll
  for (int ni = 0; ni < 5; ++ni) nm[ni] = negm[b * 80 + ni * 16 + m16];
  float* obase = SIM + ((size_t)bh * 4096 + row0 + w * 32 + quad * 4) * 80 + m16;
#pragma unroll
  for (int mi = 0; mi < 2; ++mi)
#pragma unroll
    for (int ni = 0; ni < 5; ++ni)
#pragma unroll
      for (int r = 0; r < 4; ++r)
        obase[(size_t)(mi * 16 + r) * 80 + ni * 16] = acc[mi][ni][r] + nm[ni];
}

// ---------------- lane-per-(row,head) top3 + closed-form softmax/conf + PV ----
// g = b*32768 + n*8 + h : the 8 heads of a row sit in adjacent lanes.
__global__ __launch_bounds__(256)
void attn_topk_pv_kernel(const float* __restrict__ SIM,         // [64,4096,80]
                         const float* __restrict__ vf,          // [616,512]
                         unsigned short* __restrict__ alignedb, // [32768,512] bf16
                         float* __restrict__ conf_out) {        // [32768]
  const int g = blockIdx.x * 256 + threadIdx.x;
  const int b = g >> 15;
  const int local = g & 32767;
  const int n = local >> 3, h = local & 7;
  const float* sp = SIM + ((size_t)(b * 8 + h) * 4096 + n) * 80;

  // ---- streaming top-3 (with argmax) + m4 for boundary-tie detection ----
  float m1 = -INFINITY, m2 = -INFINITY, m3 = -INFINITY, m4 = -INFINITY;
  int a1 = 0, a2 = 0, a3 = 0;
#pragma unroll
  for (int i = 0; i < 20; ++i) {
    const float4 q = ((const float4*)sp)[i];
#pragma unroll
    for (int j = 0; j < 4; ++j) {
      const float v = (j == 0) ? q.x : (j == 1) ? q.y : (j == 2) ? q.z : q.w;
      const int t = i * 4 + j;
      const bool c1 = v > m1, c2 = v > m2, c3 = v > m3, c4 = v > m4;
      m4 = c4 ? (c3 ? m3 : v) : m4;            // uses old m3
      m3 = c3 ? (c2 ? m2 : v) : m3;            // uses old m2
      a3 = c3 ? (c2 ? a2 : t) : a3;
      m2 = c2 ? (c1 ? m1 : v) : m2;            // uses old m1
      a2 = c2 ? (c1 ? a1 : t) : a2;
      m1 = c1 ? v : m1;
      a1 = c1 ? t : a1;
    }
  }

  const bool dead = (m1 == -INFINITY);         // fully-padded row
  if (dead) m1 = 0.0f;
  // any duplicate inside top-3, or a 4th value tied with the threshold
  const bool tie = (!dead) && ((m1 == m2) || (m2 == m3) || (m3 == m4));

  // ---- closed-form softmax pieces (fast path: survivors = {a1,a2,a3}) ----
  const float d2 = m2 - m1, d3 = m3 - m1;      // <= 0 (or -inf)
  const float e2 = __expf(d2), e3 = __expf(d3);  // exp(-inf) = 0
  float s0 = 1.0f + e2 + e3;
  float s1 = ((e2 > 0.f) ? e2 * d2 : 0.f) + ((e3 > 0.f) ? e3 * d3 : 0.f);
  float cntf = 1.0f + ((e2 > 0.f) ? 1.f : 0.f) + ((e3 > 0.f) ? 1.f : 0.f);

  // ---- PV: 3 dense 64-ch FMAs against L2-resident V ----
  const float w1 = dead ? 0.f : 1.f;
  const float* v1p = vf + (size_t)(b * 77 + a1) * 512 + h * 64;
  const float* v2p = vf + (size_t)(b * 77 + a2) * 512 + h * 64;
  const float* v3p = vf + (size_t)(b * 77 + a3) * 512 + h * 64;
  float4 acc[16];
#pragma unroll
  for (int i = 0; i < 16; ++i) {
    const float4 x1 = ((const float4*)v1p)[i];
    const float4 x2 = ((const float4*)v2p)[i];
    const float4 x3 = ((const float4*)v3p)[i];
    float4 r;
    r.x = fmaf(e3, x3.x, fmaf(e2, x2.x, w1 * x1.x));
    r.y = fmaf(e3, x3.y, fmaf(e2, x2.y, w1 * x1.y));
    r.z = fmaf(e3, x3.z, fmaf(e2, x2.z, w1 * x1.z));
    r.w = fmaf(e3, x3.w, fmaf(e2, x2.w, w1 * x1.w));
    acc[i] = r;
  }

  // ---- exact-tie slow path (never taken on continuous data) ----
  if (__any(tie)) {
    if (tie) {
      s0 = 0.f; s1 = 0.f; cntf = 0.f;
#pragma unroll
      for (int i = 0; i < 16; ++i) acc[i] = (float4){0.f, 0.f, 0.f, 0.f};
      for (int t = 0; t < 80; ++t) {
        const float v = sp[t];
        if (v >= m3) {
          const float e = expf(v - m1);
          if (e > 0.f) {
            s0 += e; s1 = fmaf(e, v - m1, s1); cntf += 1.f;
            const float4* vp = (const float4*)(vf + (size_t)(b * 77 + t) * 512 + h * 64);
#pragma unroll
            for (int i = 0; i < 16; ++i) {
              const float4 x = vp[i];
              acc[i].x = fmaf(e, x.x, acc[i].x);
              acc[i].y = fmaf(e, x.y, acc[i].y);
              acc[i].z = fmaf(e, x.z, acc[i].z);
              acc[i].w = fmaf(e, x.w, acc[i].w);
            }
          }
        }
      }
    }
  }

  // ---- conf from closed form: -sum p log p = log(s0) - s1/s0 ----
  const float inv = 1.0f / s0;
  const float entn = (__logf(s0) - s1 * inv) + (77.0f - cntf) * 1.8420681e-7f;
  const float ent = fmaxf(entn / __logf(fmaxf(cntf, 2.0f)), 0.0f);
  float conf_h = fminf(fmaxf(inv * (1.0f - ent), 0.0f), 1.0f);
  if (dead) conf_h = 0.f;
  float cs = conf_h;
  cs += __shfl_xor(cs, 1, 64);
  cs += __shfl_xor(cs, 2, 64);
  cs += __shfl_xor(cs, 4, 64);
  if (h == 0) {
    const float cm = fminf(fmaxf(cs * 0.125f, 0.0f), 1.0f);
    conf_out[(size_t)b * 4096 + n] = 0.35f + 0.65f * cm;
  }

  // ---- store aligned (bf16, 128B contiguous per lane) ----
  unsigned short* op = alignedb + ((size_t)b * 4096 + n) * 512 + h * 64;
#pragma unroll
  for (int i = 0; i < 8; ++i) {
    const float4 lo = acc[2 * i], hi = acc[2 * i + 1];
    uint4 pk;
    pk.x = (unsigned int)f2bf(lo.x * inv) | ((unsigned int)f2bf(lo.y * inv) << 16);
    pk.y = (unsigned int)f2bf(lo.z * inv) | ((unsigned int)f2bf(lo.w * inv) << 16);
    pk.z = (unsigned int)f2bf(hi.x * inv) | ((unsigned int)f2bf(hi.y * inv) << 16);
    pk.w = (unsigned int)f2bf(hi.z * inv) | ((unsigned int)f2bf(hi.w * inv) << 16);
    *(uint4*)(op + i * 8) = pk;
  }
}

// ---------------- bf16 MFMA GEMM: out = epi(A[M,K] @ WT[N,K]^T + bias) --------
// LDS tiles use an in-row XOR swizzle (chunk ^= row&3) applied BOTH at the
// global source address (global_load_lds writes linearly) and at ds_read.
template <int EPI>
__global__ __launch_bounds__(256)
void mfma_gemm(const unsigned short* __restrict__ A,
               const unsigned short* __restrict__ WT,
               const float* __restrict__ bias,
               void* __restrict__ outv, int M, int N, int K,
               const unsigned short* __restrict__ e0b,
               const float* __restrict__ e1f,
               const float* __restrict__ e2f,
               const float* __restrict__ scf) {
  __shared__ __align__(16) unsigned short As[128 * 32];
  __shared__ __align__(16) unsigned short Bs[128 * 32];
  const int tid = threadIdx.x;
  const int wid = tid >> 6, lane = tid & 63;
  const int wr = wid >> 1, wc = wid & 1;
  const int m16 = lane & 15, quad = lane >> 4;
  const int row0 = blockIdx.y * 128, col0 = blockIdx.x * 128;

  const floatx4 zero4 = {0.f, 0.f, 0.f, 0.f};
  floatx4 acc[4][4];
#pragma unroll
  for (int i = 0; i < 4; ++i)
#pragma unroll
    for (int j = 0; j < 4; ++j) acc[i][j] = zero4;

  // staging: thread tid owns LDS row (tid>>2), chunk (tid&3); source chunk is
  // XOR-swizzled so the swizzled ds_read below sees the right data.
  const int srow = tid >> 2;
  const int schunk = (tid & 3) ^ (srow & 3);
  const unsigned short* Ag = A + (size_t)(row0 + srow) * K + schunk * 8;
  const unsigned short* Bg = WT + (size_t)(col0 + srow) * K + schunk * 8;
  char* AsB = (char*)As + tid * 16;
  char* BsB = (char*)Bs + tid * 16;
  const int rq = quad ^ (m16 & 3);   // swizzled read chunk (row&3 == m16&3)
  const unsigned short* aP = As + (wr * 64 + m16) * 32 + rq * 8;
  const unsigned short* bP = Bs + (wc * 64 + m16) * 32 + rq * 8;

  for (int k0 = 0; k0 < K; k0 += 32) {
    __syncthreads();
    __builtin_amdgcn_global_load_lds(GPTR(Ag + k0), LPTR(AsB), 16, 0, 0);
    __builtin_amdgcn_global_load_lds(GPTR(Ag + (size_t)64 * K + k0), LPTR(AsB + 4096), 16, 0, 0);
    __builtin_amdgcn_global_load_lds(GPTR(Bg + k0), LPTR(BsB), 16, 0, 0);
    __builtin_amdgcn_global_load_lds(GPTR(Bg + (size_t)64 * K + k0), LPTR(BsB + 4096), 16, 0, 0);
    __syncthreads();
    bf16x8 af[4], bfr[4];
#pragma unroll
    for (int i = 0; i < 4; ++i) {
      af[i] = *(const bf16x8*)(aP + i * 16 * 32);
      bfr[i] = *(const bf16x8*)(bP + i * 16 * 32);
    }
#pragma unroll
    for (int mi = 0; mi < 4; ++mi)
#pragma unroll
      for (int ni = 0; ni < 4; ++ni)
        acc[mi][ni] = __builtin_amdgcn_mfma_f32_16x16x32_bf16(af[mi], bfr[ni], acc[mi][ni], 0, 0, 0);
  }

  float* outf = (float*)outv;
  unsigned short* outb = (unsigned short*)outv;
  float bb[4];
#pragma unroll
  for (int ni = 0; ni < 4; ++ni) bb[ni] = bias[col0 + wc * 64 + ni * 16 + m16];
  const float alphav = (EPI == 2) ? scf[0] : 0.f;

#pragma unroll
  for (int mi = 0; mi < 4; ++mi) {
#pragma unroll
    for (int r = 0; r < 4; ++r) {
      const int row = row0 + wr * 64 + mi * 16 + quad * 4 + r;
      float rowscale = 1.f, geo = 0.f;
      if (EPI == 1) rowscale = e1f[row];
      if (EPI == 2) geo = fminf(fmaxf(e2f[row], 0.3f), 1.0f);
#pragma unroll
      for (int ni = 0; ni < 4; ++ni) {
        const int col = col0 + wc * 64 + ni * 16 + m16;
        const size_t idx = (size_t)row * N + col;
        float o = acc[mi][ni][r] + bb[ni];
        if (EPI == 0) {
          outf[idx] = o;
        } else if (EPI == 1) {
          outf[idx] = o * rowscale;
        } else if (EPI == 2) {
          const float x = bf2f(e0b[idx]);
          const float al = e1f[idx];
          const float sg = fast_sigmoid(o);
          outf[idx] = x + alphav * sg * geo * al;
        } else if (EPI == 3) {
          outb[idx] = f2bf(fast_gelu(o));
        } else {
          outf[idx] = o + e1f[idx];
        }
      }
    }
  }
}

extern "C" void kernel_launch(void* const* d_in, const int* in_sizes, int n_in,
                              void* d_out, int out_size, void* d_ws, size_t ws_size,
                              hipStream_t stream) {
  const float* visual = (const float*)d_in[0];
  const float* text   = (const float*)d_in[1];
  const float* geo    = (const float*)d_in[2];
  const float* ln1_w  = (const float*)d_in[3];
  const float* ln1_b  = (const float*)d_in[4];
  const float* wq     = (const float*)d_in[5];
  const float* bq     = (const float*)d_in[6];
  const float* wk     = (const float*)d_in[7];
  const float* bk     = (const float*)d_in[8];
  const float* wvw    = (const float*)d_in[9];
  const float* bv     = (const float*)d_in[10];
  const float* wo     = (const float*)d_in[11];
  const float* bo     = (const float*)d_in[12];
  const float* gate_w = (const float*)d_in[13];
  const float* gate_b = (const float*)d_in[14];
  const float* logit_scale = (const float*)d_in[15];
  const float* alpha  = (const float*)d_in[16];
  const float* ln2_w  = (const float*)d_in[17];
  const float* ln2_b  = (const float*)d_in[18];
  const float* ffn_w1 = (const float*)d_in[19];
  const float* ffn_b1 = (const float*)d_in[20];
  const float* ffn_w2 = (const float*)d_in[21];
  const float* ffn_b2 = (const float*)d_in[22];
  float* out = (float*)d_out;

  char* ws = (char*)d_ws;
  // R0 (88 MB): q fp32 -> SIM fp32 -> alignedO fp32 -> GCH bf16
  float* R0            = (float*)ws;
  float* BUF2          = (float*)(ws + 88080384);             // y fp32, 64 MB
  unsigned short* Xb   = (unsigned short*)(ws + 155189248);   // 32 MB
  unsigned short* QNb  = (unsigned short*)(ws + 188743680);   // 32 MB (-> ALb later)
  unsigned short* wqT  = (unsigned short*)(ws + 222298112);
  unsigned short* woT  = wqT + 262144;
  unsigned short* gateT = woT + 262144;
  unsigned short* w1T  = gateT + 262144;                      // [2048,512]
  unsigned short* w2T  = w1T + 1048576;                       // [512,2048]
  unsigned short* KHb  = w2T + 1048576;                       // [64,80,64] bf16
  float* VF   = (float*)(ws + 228884480);                     // [616,512]
  float* NEGM = (float*)(ws + 230146048);                     // [8,80]
  float* CONF = (float*)(ws + 230148608);                     // [32768]

  float* Qf = R0;
  float* SIM = R0;
  float* AO = R0;
  unsigned short* ALb = QNb;   // aliased: QN dead after sim_kernel

  // weight transposes -> bf16 [N,K]
  transpose_bf16_kernel<<<dim3(16, 16), 256, 0, stream>>>(wq, wqT, 512, 512);
  transpose_bf16_kernel<<<dim3(16, 16), 256, 0, stream>>>(wo, woT, 512, 512);
  transpose_bf16_kernel<<<dim3(16, 16), 256, 0, stream>>>(gate_w, gateT, 512, 512);
  transpose_bf16_kernel<<<dim3(64, 16), 256, 0, stream>>>(ffn_w1, w1T, 512, 2048);
  transpose_bf16_kernel<<<dim3(16, 64), 256, 0, stream>>>(ffn_w2, w2T, 2048, 512);

  // 1. x = LN1(visual) -> bf16
  ln_bf16_kernel<<<MTOT / 4, 256, 0, stream>>>(visual, ln1_w, ln1_b, Xb);
  // 2. text projections (k bf16 head-major [.,80,64], negmask per (b,t))
  text_proj_kernel<<<8 * TT, 256, 0, stream>>>(text, wk, bk, wvw, bv, KHb, VF, NEGM);
  kpad_zero_kernel<<<48, 256, 0, stream>>>(KHb, NEGM);
  // 3. q = x @ wq + bq (fp32)
  mfma_gemm<0><<<dim3(4, 256), 256, 0, stream>>>(Xb, wqT, bq, Qf, MTOT, 512, 512,
                                                 nullptr, nullptr, nullptr, nullptr);
  // 4. qn = l2norm(q) * scale -> bf16
  qnorm_kernel<<<MTOT / 4, 256, 0, stream>>>(Qf, logit_scale, QNb);
  // 5. SIM = qn . k^T + negmask  (MFMA)   [overwrites Qf - dead]
  sim_kernel<<<dim3(32, 64), 256, 0, stream>>>(QNb, KHb, NEGM, SIM);
  // 6. lane-per-(row,head) topk/softmax/conf/PV -> ALb (bf16, overlays QNb), CONF
  attn_topk_pv_kernel<<<1024, 256, 0, stream>>>(SIM, VF, ALb, CONF);
  // 7. alignedO = (aligned @ wo + bo) * conf -> AO fp32 (overlays SIM - dead)
  mfma_gemm<1><<<dim3(4, 256), 256, 0, stream>>>(ALb, woT, bo, AO, MTOT, 512, 512,
                                                 nullptr, CONF, nullptr, nullptr);
  // 8. y = x + alpha*sigmoid(x@gate_w+gate_b)*geo*alignedO -> BUF2
  mfma_gemm<2><<<dim3(4, 256), 256, 0, stream>>>(Xb, gateT, gate_b, BUF2, MTOT, 512, 512,
                                                 Xb, AO, geo, alpha);
  // 9. h = LN2(y) -> Xb (bf16)
  ln_bf16_kernel<<<MTOT / 4, 256, 0, stream>>>(BUF2, ln2_w, ln2_b, Xb);
  // 10. FFN in 2 chunks of 16384 rows; GCH (bf16) overlays R0 (AO dead)
  unsigned short* GCH = (unsigned short*)R0;
  for (int ch = 0; ch < 2; ++ch) {
    const size_t off = (size_t)ch * 16384;
    mfma_gemm<3><<<dim3(16, 128), 256, 0, stream>>>(Xb + off * 512, w1T, ffn_b1, GCH,
                                                    16384, 2048, 512,
                                                    nullptr, nullptr, nullptr, nullptr);
    mfma_gemm<4><<<dim3(4, 128), 256, 0, stream>>>(GCH, w2T, ffn_b2, out + off * 512,
                                                   16384, 512, 2048,
                                                   nullptr, BUF2 + off * 512, nullptr, nullptr);
  }
}

// Round 3
// 664.889 us; speedup vs baseline: 1.2081x; 1.0616x over previous
//
#include <hip/hip_runtime.h>
#include <hip/hip_bf16.h>
#include <math.h>

#define TT 77
#define MTOT 32768

typedef __attribute__((ext_vector_type(8))) short bf16x8;
typedef __attribute__((ext_vector_type(4))) float floatx4;

#define GPTR(p) ((const __attribute__((address_space(1))) void*)(p))
#define LPTR(p) ((__attribute__((address_space(3))) void*)(p))

__device__ __forceinline__ float wred_sum(float v) {
#pragma unroll
  for (int o = 32; o >= 1; o >>= 1) v += __shfl_xor(v, o, 64);
  return v;
}

__device__ __forceinline__ unsigned short f2bf(float f) {
  unsigned int u = __float_as_uint(f);
  unsigned int r = (u + 0x7fffu + ((u >> 16) & 1u)) >> 16;
  return (unsigned short)r;
}
__device__ __forceinline__ float bf2f(unsigned short h) {
  return __uint_as_float(((unsigned int)h) << 16);
}

// fast erf-based GELU: Abramowitz-Stegun 7.1.26, |err| <= 1.5e-7 (way below bf16 lsb)
__device__ __forceinline__ float fast_gelu(float o) {
  const float z = fabsf(o) * 0.70710678118654752f;
  const float t = __builtin_amdgcn_rcpf(fmaf(0.3275911f, z, 1.0f));
  float p = fmaf(1.061405429f, t, -1.453152027f);
  p = fmaf(p, t, 1.421413741f);
  p = fmaf(p, t, -0.284496736f);
  p = fmaf(p, t, 0.254829592f);
  p = p * t;
  const float erfz = fmaf(-p, __expf(-z * z), 1.0f);   // erf(|o|/sqrt2)
  const float s = __builtin_copysignf(erfz, o);
  return 0.5f * o * (1.0f + s);
}

__device__ __forceinline__ float fast_sigmoid(float o) {
  return __builtin_amdgcn_rcpf(1.0f + __expf(-o));
}

// ---------------- LayerNorm over rows of 512 -> bf16 out (one wave per row) ---
__global__ __launch_bounds__(256)
void ln_bf16_kernel(const float* __restrict__ in, const float* __restrict__ gw,
                    const float* __restrict__ gb, unsigned short* __restrict__ out) {
  const int wv = threadIdx.x >> 6, lane = threadIdx.x & 63;
  const size_t row = (size_t)blockIdx.x * 4 + wv;
  const float* p = in + row * 512 + lane * 8;
  float4 a = *(const float4*)p;
  float4 b = *(const float4*)(p + 4);
  float s = a.x + a.y + a.z + a.w + b.x + b.y + b.z + b.w;
  float mu = wred_sum(s) * (1.0f / 512.0f);
  float d[8] = {a.x - mu, a.y - mu, a.z - mu, a.w - mu,
                b.x - mu, b.y - mu, b.z - mu, b.w - mu};
  float ss = 0.f;
#pragma unroll
  for (int i = 0; i < 8; ++i) ss = fmaf(d[i], d[i], ss);
  float var = wred_sum(ss) * (1.0f / 512.0f);
  float rstd = rsqrtf(var + 1e-5f);
  float4 w0 = *(const float4*)(gw + lane * 8);
  float4 w1 = *(const float4*)(gw + lane * 8 + 4);
  float4 c0 = *(const float4*)(gb + lane * 8);
  float4 c1 = *(const float4*)(gb + lane * 8 + 4);
  float o[8];
  o[0] = d[0] * rstd * w0.x + c0.x;  o[1] = d[1] * rstd * w0.y + c0.y;
  o[2] = d[2] * rstd * w0.z + c0.z;  o[3] = d[3] * rstd * w0.w + c0.w;
  o[4] = d[4] * rstd * w1.x + c1.x;  o[5] = d[5] * rstd * w1.y + c1.y;
  o[6] = d[6] * rstd * w1.z + c1.z;  o[7] = d[7] * rstd * w1.w + c1.w;
  __align__(16) unsigned short ob[8];
#pragma unroll
  for (int i = 0; i < 8; ++i) ob[i] = f2bf(o[i]);
  *(uint4*)(out + row * 512 + lane * 8) = *(const uint4*)ob;
}

// ---------------- q row: L2-normalize + fold sim scale + bf16 ------------------
__global__ __launch_bounds__(256)
void qnorm_kernel(const float* __restrict__ q, const float* __restrict__ logit_scale,
                  unsigned short* __restrict__ qnb) {
  const int wv = threadIdx.x >> 6, lane = threadIdx.x & 63;
  const size_t row = (size_t)blockIdx.x * 4 + wv;
  const float ls = fminf(fmaxf(logit_scale[0], -2.0f), 2.0f);
  const float scale = expf(ls) * 0.125f;
  const float* p = q + row * 512 + lane * 8;
  float4 a = *(const float4*)p;
  float4 b = *(const float4*)(p + 4);
  float ss = a.x * a.x + a.y * a.y + a.z * a.z + a.w * a.w +
             b.x * b.x + b.y * b.y + b.z * b.z + b.w * b.w;
  ss = wred_sum(ss);
  const float nsc = scale / fmaxf(sqrtf(ss), 1e-6f);
  float o[8] = {a.x * nsc, a.y * nsc, a.z * nsc, a.w * nsc,
                b.x * nsc, b.y * nsc, b.z * nsc, b.w * nsc};
  __align__(16) unsigned short ob[8];
#pragma unroll
  for (int i = 0; i < 8; ++i) ob[i] = f2bf(o[i]);
  *(uint4*)(qnb + row * 512 + lane * 8) = *(const uint4*)ob;
}

// ---------------- weight transpose + bf16 convert: W[K,N] -> WT[N,K] ----------
__global__ __launch_bounds__(256)
void transpose_bf16_kernel(const float* __restrict__ W, unsigned short* __restrict__ WTb,
                           int K, int N) {
  __shared__ float s[32][33];
  const int tx = threadIdx.x & 31, ty = threadIdx.x >> 5;  // ty 0..7
  const int n0 = blockIdx.x * 32, k0 = blockIdx.y * 32;
#pragma unroll
  for (int j = 0; j < 4; ++j)
    s[ty + 8 * j][tx] = W[(size_t)(k0 + ty + 8 * j) * N + n0 + tx];
  __syncthreads();
#pragma unroll
  for (int j = 0; j < 4; ++j)
    WTb[(size_t)(n0 + ty + 8 * j) * K + k0 + tx] = f2bf(s[tx][ty + 8 * j]);
}

// ---------------- pair transpose: W[K,N] -> hi/lo split bf16 WT[N,K] ----------
__global__ __launch_bounds__(256)
void transpose_pair_kernel(const float* __restrict__ W,
                           unsigned short* __restrict__ WTh,
                           unsigned short* __restrict__ WTl, int K, int N) {
  __shared__ float s[32][33];
  const int tx = threadIdx.x & 31, ty = threadIdx.x >> 5;  // ty 0..7
  const int n0 = blockIdx.x * 32, k0 = blockIdx.y * 32;
#pragma unroll
  for (int j = 0; j < 4; ++j)
    s[ty + 8 * j][tx] = W[(size_t)(k0 + ty + 8 * j) * N + n0 + tx];
  __syncthreads();
#pragma unroll
  for (int j = 0; j < 4; ++j) {
    const float a = s[tx][ty + 8 * j];
    const unsigned short hi = f2bf(a);
    WTh[(size_t)(n0 + ty + 8 * j) * K + k0 + tx] = hi;
    WTl[(size_t)(n0 + ty + 8 * j) * K + k0 + tx] = f2bf(a - bf2f(hi));
  }
}

// ---------------- text -> hi/lo bf16 split (rows 616..639 zeroed) + pad mask --
__global__ __launch_bounds__(256)
void text_cvt_kernel(const float* __restrict__ text,
                     unsigned short* __restrict__ thi,
                     unsigned short* __restrict__ tlo,
                     float* __restrict__ negm) {
  const int wv = threadIdx.x >> 6, lane = threadIdx.x & 63;
  const int row = blockIdx.x * 4 + wv;       // 0..639
  if (row >= 616) {
    const uint4 z = {0u, 0u, 0u, 0u};
    *(uint4*)(thi + (size_t)row * 512 + lane * 8) = z;
    *(uint4*)(tlo + (size_t)row * 512 + lane * 8) = z;
    return;
  }
  const float* p = text + (size_t)row * 512 + lane * 8;
  float4 a = *(const float4*)p;
  float4 b = *(const float4*)(p + 4);
  float v[8] = {a.x, a.y, a.z, a.w, b.x, b.y, b.z, b.w};
  float ab = 0.f;
#pragma unroll
  for (int i = 0; i < 8; ++i) ab += fabsf(v[i]);
  ab = wred_sum(ab);
  __align__(16) unsigned short hb[8];
  __align__(16) unsigned short lb[8];
#pragma unroll
  for (int i = 0; i < 8; ++i) {
    hb[i] = f2bf(v[i]);
    lb[i] = f2bf(v[i] - bf2f(hb[i]));
  }
  *(uint4*)(thi + (size_t)row * 512 + lane * 8) = *(const uint4*)hb;
  *(uint4*)(tlo + (size_t)row * 512 + lane * 8) = *(const uint4*)lb;
  if (lane == 0) {
    const int bb = row / 77, t = row - bb * 77;
    negm[bb * 80 + t] = (ab <= 1e-6f) ? -INFINITY : 0.0f;
  }
}

// ---------------- kv projection GEMM, split-bf16 (~fp32 exact) ----------------
// out[640,1024] = (THi+TLo)[640,512] @ (WTh+WTl)[1024,512]^T + bias
// acc = AH*BH + AH*BL + AL*BH  (AL*BL term ~2^-18, dropped)
__global__ __launch_bounds__(256)
void kv_gemm(const unsigned short* __restrict__ AH,
             const unsigned short* __restrict__ AL,
             const unsigned short* __restrict__ BH,
             const unsigned short* __restrict__ BL,
             const float* __restrict__ bk, const float* __restrict__ bv,
             float* __restrict__ outp) {
  const int K = 512;
  __shared__ __align__(16) unsigned short AsH[128 * 32];
  __shared__ __align__(16) unsigned short AsL[128 * 32];
  __shared__ __align__(16) unsigned short BsH[128 * 32];
  __shared__ __align__(16) unsigned short BsL[128 * 32];
  const int tid = threadIdx.x;
  const int wid = tid >> 6, lane = tid & 63;
  const int wr = wid >> 1, wc = wid & 1;
  const int m16 = lane & 15, quad = lane >> 4;
  const int row0 = blockIdx.y * 128, col0 = blockIdx.x * 128;

  const floatx4 zero4 = {0.f, 0.f, 0.f, 0.f};
  floatx4 acc[4][4];
#pragma unroll
  for (int i = 0; i < 4; ++i)
#pragma unroll
    for (int j = 0; j < 4; ++j) acc[i][j] = zero4;

  const int srow = tid >> 2;
  const int schunk = (tid & 3) ^ (srow & 3);
  const unsigned short* AgH = AH + (size_t)(row0 + srow) * K + schunk * 8;
  const unsigned short* AgL = AL + (size_t)(row0 + srow) * K + schunk * 8;
  const unsigned short* BgH = BH + (size_t)(col0 + srow) * K + schunk * 8;
  const unsigned short* BgL = BL + (size_t)(col0 + srow) * K + schunk * 8;
  char* AsHB = (char*)AsH + tid * 16;
  char* AsLB = (char*)AsL + tid * 16;
  char* BsHB = (char*)BsH + tid * 16;
  char* BsLB = (char*)BsL + tid * 16;
  const int rq = quad ^ (m16 & 3);
  const int aOfs = (wr * 64 + m16) * 32 + rq * 8;
  const int bOfs = (wc * 64 + m16) * 32 + rq * 8;

  for (int k0 = 0; k0 < K; k0 += 32) {
    __syncthreads();
    __builtin_amdgcn_global_load_lds(GPTR(AgH + k0), LPTR(AsHB), 16, 0, 0);
    __builtin_amdgcn_global_load_lds(GPTR(AgH + (size_t)64 * K + k0), LPTR(AsHB + 4096), 16, 0, 0);
    __builtin_amdgcn_global_load_lds(GPTR(AgL + k0), LPTR(AsLB), 16, 0, 0);
    __builtin_amdgcn_global_load_lds(GPTR(AgL + (size_t)64 * K + k0), LPTR(AsLB + 4096), 16, 0, 0);
    __builtin_amdgcn_global_load_lds(GPTR(BgH + k0), LPTR(BsHB), 16, 0, 0);
    __builtin_amdgcn_global_load_lds(GPTR(BgH + (size_t)64 * K + k0), LPTR(BsHB + 4096), 16, 0, 0);
    __builtin_amdgcn_global_load_lds(GPTR(BgL + k0), LPTR(BsLB), 16, 0, 0);
    __builtin_amdgcn_global_load_lds(GPTR(BgL + (size_t)64 * K + k0), LPTR(BsLB + 4096), 16, 0, 0);
    __syncthreads();
    bf16x8 afH[4], afL[4], bfH[4], bfL[4];
#pragma unroll
    for (int i = 0; i < 4; ++i) {
      afH[i] = *(const bf16x8*)(AsH + aOfs + i * 16 * 32);
      afL[i] = *(const bf16x8*)(AsL + aOfs + i * 16 * 32);
      bfH[i] = *(const bf16x8*)(BsH + bOfs + i * 16 * 32);
      bfL[i] = *(const bf16x8*)(BsL + bOfs + i * 16 * 32);
    }
#pragma unroll
    for (int mi = 0; mi < 4; ++mi)
#pragma unroll
      for (int ni = 0; ni < 4; ++ni) {
        acc[mi][ni] = __builtin_amdgcn_mfma_f32_16x16x32_bf16(afH[mi], bfH[ni], acc[mi][ni], 0, 0, 0);
        acc[mi][ni] = __builtin_amdgcn_mfma_f32_16x16x32_bf16(afH[mi], bfL[ni], acc[mi][ni], 0, 0, 0);
        acc[mi][ni] = __builtin_amdgcn_mfma_f32_16x16x32_bf16(afL[mi], bfH[ni], acc[mi][ni], 0, 0, 0);
      }
  }

  const float* bp = (col0 < 512) ? bk : bv;
  const int cbase = (col0 < 512) ? col0 : col0 - 512;
  float bb[4];
#pragma unroll
  for (int ni = 0; ni < 4; ++ni) bb[ni] = bp[cbase + wc * 64 + ni * 16 + m16];
#pragma unroll
  for (int mi = 0; mi < 4; ++mi)
#pragma unroll
    for (int r = 0; r < 4; ++r) {
      const int row = row0 + wr * 64 + mi * 16 + quad * 4 + r;
#pragma unroll
      for (int ni = 0; ni < 4; ++ni) {
        const int col = col0 + wc * 64 + ni * 16 + m16;
        outp[(size_t)row * 1024 + col] = acc[mi][ni][r] + bb[ni];
      }
    }
}

// ---------------- k rows: L2-normalize -> head-major bf16 ---------------------
__global__ __launch_bounds__(256)
void knorm_kernel(const float* __restrict__ KV,     // [640,1024], k = cols 0..511
                  unsigned short* __restrict__ khb) {  // [B,8,80,64]
  const int wv = threadIdx.x >> 6, lane = threadIdx.x & 63;
  const int row = blockIdx.x * 4 + wv;   // 0..615
  const float* p = KV + (size_t)row * 1024 + lane * 8;
  float4 a = *(const float4*)p;
  float4 b = *(const float4*)(p + 4);
  float v[8] = {a.x, a.y, a.z, a.w, b.x, b.y, b.z, b.w};
  float ss = 0.f;
#pragma unroll
  for (int i = 0; i < 8; ++i) ss = fmaf(v[i], v[i], ss);
  ss = wred_sum(ss);
  const float sc = 1.0f / fmaxf(sqrtf(ss), 1e-6f);
  const int bb = row / 77, t = row - bb * 77;
  const int c = lane * 8, h = c >> 6, d = c & 63;
  __align__(16) unsigned short ob[8];
#pragma unroll
  for (int i = 0; i < 8; ++i) ob[i] = f2bf(v[i] * sc);
  *(uint4*)(khb + (((size_t)bb * 8 + h) * 80 + t) * 64 + d) = *(const uint4*)ob;
}

// ---------------- zero the k pad rows (t = 77..79) + -inf negmask there -------
__global__ __launch_bounds__(256)
void kpad_zero_kernel(unsigned short* __restrict__ khb, float* __restrict__ negm) {
  // 64 (b,h) * 3 rows * 64 ch = 12288 elements
  const int i = blockIdx.x * 256 + threadIdx.x;
  const int bh = i / 192, rem = i - bh * 192;
  const int t = 77 + rem / 64, d = rem & 63;
  khb[(((size_t)bh) * 80 + t) * 64 + d] = 0;
  if (i < 24) negm[(i / 3) * 80 + 77 + (i % 3)] = -INFINITY;
}

// ---------------- sims via MFMA: SIM[b,h,n,80] = qn . k^T + negmask -----------
__global__ __launch_bounds__(256)
void sim_kernel(const unsigned short* __restrict__ qnb,   // [32768,512] bf16 scaled
                const unsigned short* __restrict__ khb,   // [64,80,64] bf16
                const float* __restrict__ negm,           // [8,80]
                float* __restrict__ SIM) {                // [64,4096,80] fp32
  __shared__ __align__(16) unsigned short As[128 * 72];
  __shared__ __align__(16) unsigned short Bs[80 * 72];
  const int bh = blockIdx.y;           // b*8+h
  const int b = bh >> 3, h = bh & 7;
  const int row0 = blockIdx.x * 128;   // within 4096
  const int tid = threadIdx.x;
  // stage A: 128 rows x 64 bf16 (2 threads per row, 64B each)
  {
    const int r = tid >> 1, half = tid & 1;
    const unsigned short* src = qnb + ((size_t)b * 4096 + row0 + r) * 512 + h * 64 + half * 32;
    unsigned short* dst = As + r * 72 + half * 32;
    *(uint4*)dst = *(const uint4*)src;
    *(uint4*)(dst + 8) = *(const uint4*)(src + 8);
    *(uint4*)(dst + 16) = *(const uint4*)(src + 16);
    *(uint4*)(dst + 24) = *(const uint4*)(src + 24);
  }
  // stage B: 80 rows x 64 bf16
  if (tid < 160) {
    const int r = tid >> 1, half = tid & 1;
    const unsigned short* src = khb + ((size_t)bh * 80 + r) * 64 + half * 32;
    unsigned short* dst = Bs + r * 72 + half * 32;
    *(uint4*)dst = *(const uint4*)src;
    *(uint4*)(dst + 8) = *(const uint4*)(src + 8);
    *(uint4*)(dst + 16) = *(const uint4*)(src + 16);
    *(uint4*)(dst + 24) = *(const uint4*)(src + 24);
  }
  __syncthreads();
  const int w = tid >> 6, lane = tid & 63;
  const int m16 = lane & 15, quad = lane >> 4;
  const unsigned short* aBase = As + (w * 32 + m16) * 72 + quad * 8;
  const unsigned short* bBase = Bs + m16 * 72 + quad * 8;
  bf16x8 af[2][2], bf[5][2];
#pragma unroll
  for (int mi = 0; mi < 2; ++mi)
#pragma unroll
    for (int kk = 0; kk < 2; ++kk)
      af[mi][kk] = *(const bf16x8*)(aBase + mi * 16 * 72 + kk * 32);
#pragma unroll
  for (int ni = 0; ni < 5; ++ni)
#pragma unroll
    for (int kk = 0; kk < 2; ++kk)
      bf[ni][kk] = *(const bf16x8*)(bBase + ni * 16 * 72 + kk * 32);
  const floatx4 zero4 = {0.f, 0.f, 0.f, 0.f};
  floatx4 acc[2][5];
#pragma unroll
  for (int mi = 0; mi < 2; ++mi)
#pragma unroll
    for (int ni = 0; ni < 5; ++ni) acc[mi][ni] = zero4;
#pragma unroll
  for (int kk = 0; kk < 2; ++kk)
#pragma unroll
    for (int mi = 0; mi < 2; ++mi)
#pragma unroll
      for (int ni = 0; ni < 5; ++ni)
        acc[mi][ni] = __builtin_amdgcn_mfma_f32_16x16x32_bf16(af[mi][kk], bf[ni][kk], acc[mi][ni], 0, 0, 0);
  float nm[5];
#pragma unroll
  for (int ni = 0; ni < 5; ++ni) nm[ni] = negm[b * 80 + ni * 16 + m16];
  float* obase = SIM + ((size_t)bh * 4096 + row0 + w * 32 + quad * 4) * 80 + m16;
#pragma unroll
  for (int mi = 0; mi < 2; ++mi)
#pragma unroll
    for (int ni = 0; ni < 5; ++ni)
#pragma unroll
      for (int r = 0; r < 4; ++r)
        obase[(size_t)(mi * 16 + r) * 80 + ni * 16] = acc[mi][ni][r] + nm[ni];
}

// ---------------- lane-per-(row,head) top3 + closed-form softmax/conf + PV ----
// g = b*32768 + n*8 + h : the 8 heads of a row sit in adjacent lanes.
// vf points at KV+512 (v block), row stride 1024.
__global__ __launch_bounds__(256)
void attn_topk_pv_kernel(const float* __restrict__ SIM,         // [64,4096,80]
                         const float* __restrict__ vf,          // KV+512, stride 1024
                         unsigned short* __restrict__ alignedb, // [32768,512] bf16
                         float* __restrict__ conf_out) {        // [32768]
  const int g = blockIdx.x * 256 + threadIdx.x;
  const int b = g >> 15;
  const int local = g & 32767;
  const int n = local >> 3, h = local & 7;
  const float* sp = SIM + ((size_t)(b * 8 + h) * 4096 + n) * 80;

  // ---- streaming top-3 (with argmax) + m4 for boundary-tie detection ----
  float m1 = -INFINITY, m2 = -INFINITY, m3 = -INFINITY, m4 = -INFINITY;
  int a1 = 0, a2 = 0, a3 = 0;
#pragma unroll
  for (int i = 0; i < 20; ++i) {
    const float4 q = ((const float4*)sp)[i];
#pragma unroll
    for (int j = 0; j < 4; ++j) {
      const float v = (j == 0) ? q.x : (j == 1) ? q.y : (j == 2) ? q.z : q.w;
      const int t = i * 4 + j;
      const bool c1 = v > m1, c2 = v > m2, c3 = v > m3, c4 = v > m4;
      m4 = c4 ? (c3 ? m3 : v) : m4;            // uses old m3
      m3 = c3 ? (c2 ? m2 : v) : m3;            // uses old m2
      a3 = c3 ? (c2 ? a2 : t) : a3;
      m2 = c2 ? (c1 ? m1 : v) : m2;            // uses old m1
      a2 = c2 ? (c1 ? a1 : t) : a2;
      m1 = c1 ? v : m1;
      a1 = c1 ? t : a1;
    }
  }

  const bool dead = (m1 == -INFINITY);         // fully-padded row
  if (dead) m1 = 0.0f;
  // any duplicate inside top-3, or a 4th value tied with the threshold
  const bool tie = (!dead) && ((m1 == m2) || (m2 == m3) || (m3 == m4));

  // ---- closed-form softmax pieces (fast path: survivors = {a1,a2,a3}) ----
  const float d2 = m2 - m1, d3 = m3 - m1;      // <= 0 (or -inf)
  const float e2 = __expf(d2), e3 = __expf(d3);  // exp(-inf) = 0
  float s0 = 1.0f + e2 + e3;
  float s1 = ((e2 > 0.f) ? e2 * d2 : 0.f) + ((e3 > 0.f) ? e3 * d3 : 0.f);
  float cntf = 1.0f + ((e2 > 0.f) ? 1.f : 0.f) + ((e3 > 0.f) ? 1.f : 0.f);

  // ---- PV: 3 dense 64-ch FMAs against L2-resident V ----
  const float w1 = dead ? 0.f : 1.f;
  const float* v1p = vf + (size_t)(b * 77 + a1) * 1024 + h * 64;
  const float* v2p = vf + (size_t)(b * 77 + a2) * 1024 + h * 64;
  const float* v3p = vf + (size_t)(b * 77 + a3) * 1024 + h * 64;
  float4 acc[16];
#pragma unroll
  for (int i = 0; i < 16; ++i) {
    const float4 x1 = ((const float4*)v1p)[i];
    const float4 x2 = ((const float4*)v2p)[i];
    const float4 x3 = ((const float4*)v3p)[i];
    float4 r;
    r.x = fmaf(e3, x3.x, fmaf(e2, x2.x, w1 * x1.x));
    r.y = fmaf(e3, x3.y, fmaf(e2, x2.y, w1 * x1.y));
    r.z = fmaf(e3, x3.z, fmaf(e2, x2.z, w1 * x1.z));
    r.w = fmaf(e3, x3.w, fmaf(e2, x2.w, w1 * x1.w));
    acc[i] = r;
  }

  // ---- exact-tie slow path (never taken on continuous data) ----
  if (__any(tie)) {
    if (tie) {
      s0 = 0.f; s1 = 0.f; cntf = 0.f;
#pragma unroll
      for (int i = 0; i < 16; ++i) acc[i] = (float4){0.f, 0.f, 0.f, 0.f};
      for (int t = 0; t < 80; ++t) {
        const float v = sp[t];
        if (v >= m3) {
          const float e = expf(v - m1);
          if (e > 0.f) {
            s0 += e; s1 = fmaf(e, v - m1, s1); cntf += 1.f;
            const float4* vp = (const float4*)(vf + (size_t)(b * 77 + t) * 1024 + h * 64);
#pragma unroll
            for (int i = 0; i < 16; ++i) {
              const float4 x = vp[i];
              acc[i].x = fmaf(e, x.x, acc[i].x);
              acc[i].y = fmaf(e, x.y, acc[i].y);
              acc[i].z = fmaf(e, x.z, acc[i].z);
              acc[i].w = fmaf(e, x.w, acc[i].w);
            }
          }
        }
      }
    }
  }

  // ---- conf from closed form: -sum p log p = log(s0) - s1/s0 ----
  const float inv = 1.0f / s0;
  const float entn = (__logf(s0) - s1 * inv) + (77.0f - cntf) * 1.8420681e-7f;
  const float ent = fmaxf(entn / __logf(fmaxf(cntf, 2.0f)), 0.0f);
  float conf_h = fminf(fmaxf(inv * (1.0f - ent), 0.0f), 1.0f);
  if (dead) conf_h = 0.f;
  float cs = conf_h;
  cs += __shfl_xor(cs, 1, 64);
  cs += __shfl_xor(cs, 2, 64);
  cs += __shfl_xor(cs, 4, 64);
  if (h == 0) {
    const float cm = fminf(fmaxf(cs * 0.125f, 0.0f), 1.0f);
    conf_out[(size_t)b * 4096 + n] = 0.35f + 0.65f * cm;
  }

  // ---- store aligned (bf16, 128B contiguous per lane) ----
  unsigned short* op = alignedb + ((size_t)b * 4096 + n) * 512 + h * 64;
#pragma unroll
  for (int i = 0; i < 8; ++i) {
    const float4 lo = acc[2 * i], hi = acc[2 * i + 1];
    uint4 pk;
    pk.x = (unsigned int)f2bf(lo.x * inv) | ((unsigned int)f2bf(lo.y * inv) << 16);
    pk.y = (unsigned int)f2bf(lo.z * inv) | ((unsigned int)f2bf(lo.w * inv) << 16);
    pk.z = (unsigned int)f2bf(hi.x * inv) | ((unsigned int)f2bf(hi.y * inv) << 16);
    pk.w = (unsigned int)f2bf(hi.z * inv) | ((unsigned int)f2bf(hi.w * inv) << 16);
    *(uint4*)(op + i * 8) = pk;
  }
}

// ---------------- bf16 MFMA GEMM: out = epi(A[M,K] @ WT[N,K]^T + bias) --------
// LDS tiles use an in-row XOR swizzle (chunk ^= row&3) applied BOTH at the
// global source address (global_load_lds writes linearly) and at ds_read.
template <int EPI>
__global__ __launch_bounds__(256)
void mfma_gemm(const unsigned short* __restrict__ A,
               const unsigned short* __restrict__ WT,
               const float* __restrict__ bias,
               void* __restrict__ outv, int M, int N, int K,
               const unsigned short* __restrict__ e0b,
               const float* __restrict__ e1f,
               const float* __restrict__ e2f,
               const float* __restrict__ scf) {
  __shared__ __align__(16) unsigned short As[128 * 32];
  __shared__ __align__(16) unsigned short Bs[128 * 32];
  const int tid = threadIdx.x;
  const int wid = tid >> 6, lane = tid & 63;
  const int wr = wid >> 1, wc = wid & 1;
  const int m16 = lane & 15, quad = lane >> 4;
  const int row0 = blockIdx.y * 128, col0 = blockIdx.x * 128;

  const floatx4 zero4 = {0.f, 0.f, 0.f, 0.f};
  floatx4 acc[4][4];
#pragma unroll
  for (int i = 0; i < 4; ++i)
#pragma unroll
    for (int j = 0; j < 4; ++j) acc[i][j] = zero4;

  // staging: thread tid owns LDS row (tid>>2), chunk (tid&3); source chunk is
  // XOR-swizzled so the swizzled ds_read below sees the right data.
  const int srow = tid >> 2;
  const int schunk = (tid & 3) ^ (srow & 3);
  const unsigned short* Ag = A + (size_t)(row0 + srow) * K + schunk * 8;
  const unsigned short* Bg = WT + (size_t)(col0 + srow) * K + schunk * 8;
  char* AsB = (char*)As + tid * 16;
  char* BsB = (char*)Bs + tid * 16;
  const int rq = quad ^ (m16 & 3);   // swizzled read chunk (row&3 == m16&3)
  const unsigned short* aP = As + (wr * 64 + m16) * 32 + rq * 8;
  const unsigned short* bP = Bs + (wc * 64 + m16) * 32 + rq * 8;

  for (int k0 = 0; k0 < K; k0 += 32) {
    __syncthreads();
    __builtin_amdgcn_global_load_lds(GPTR(Ag + k0), LPTR(AsB), 16, 0, 0);
    __builtin_amdgcn_global_load_lds(GPTR(Ag + (size_t)64 * K + k0), LPTR(AsB + 4096), 16, 0, 0);
    __builtin_amdgcn_global_load_lds(GPTR(Bg + k0), LPTR(BsB), 16, 0, 0);
    __builtin_amdgcn_global_load_lds(GPTR(Bg + (size_t)64 * K + k0), LPTR(BsB + 4096), 16, 0, 0);
    __syncthreads();
    bf16x8 af[4], bfr[4];
#pragma unroll
    for (int i = 0; i < 4; ++i) {
      af[i] = *(const bf16x8*)(aP + i * 16 * 32);
      bfr[i] = *(const bf16x8*)(bP + i * 16 * 32);
    }
#pragma unroll
    for (int mi = 0; mi < 4; ++mi)
#pragma unroll
      for (int ni = 0; ni < 4; ++ni)
        acc[mi][ni] = __builtin_amdgcn_mfma_f32_16x16x32_bf16(af[mi], bfr[ni], acc[mi][ni], 0, 0, 0);
  }

  float* outf = (float*)outv;
  unsigned short* outb = (unsigned short*)outv;
  float bb[4];
#pragma unroll
  for (int ni = 0; ni < 4; ++ni) bb[ni] = bias[col0 + wc * 64 + ni * 16 + m16];
  const float alphav = (EPI == 2) ? scf[0] : 0.f;

#pragma unroll
  for (int mi = 0; mi < 4; ++mi) {
#pragma unroll
    for (int r = 0; r < 4; ++r) {
      const int row = row0 + wr * 64 + mi * 16 + quad * 4 + r;
      float rowscale = 1.f, geo = 0.f;
      if (EPI == 1) rowscale = e1f[row];
      if (EPI == 2) geo = fminf(fmaxf(e2f[row], 0.3f), 1.0f);
#pragma unroll
      for (int ni = 0; ni < 4; ++ni) {
        const int col = col0 + wc * 64 + ni * 16 + m16;
        const size_t idx = (size_t)row * N + col;
        float o = acc[mi][ni][r] + bb[ni];
        if (EPI == 0) {
          outf[idx] = o;
        } else if (EPI == 1) {
          outf[idx] = o * rowscale;
        } else if (EPI == 2) {
          const float x = bf2f(e0b[idx]);
          const float al = e1f[idx];
          const float sg = fast_sigmoid(o);
          outf[idx] = x + alphav * sg * geo * al;
        } else if (EPI == 3) {
          outb[idx] = f2bf(fast_gelu(o));
        } else {
          outf[idx] = o + e1f[idx];
        }
      }
    }
  }
}

extern "C" void kernel_launch(void* const* d_in, const int* in_sizes, int n_in,
                              void* d_out, int out_size, void* d_ws, size_t ws_size,
                              hipStream_t stream) {
  const float* visual = (const float*)d_in[0];
  const float* text   = (const float*)d_in[1];
  const float* geo    = (const float*)d_in[2];
  const float* ln1_w  = (const float*)d_in[3];
  const float* ln1_b  = (const float*)d_in[4];
  const float* wq     = (const float*)d_in[5];
  const float* bq     = (const float*)d_in[6];
  const float* wk     = (const float*)d_in[7];
  const float* bk     = (const float*)d_in[8];
  const float* wvw    = (const float*)d_in[9];
  const float* bv     = (const float*)d_in[10];
  const float* wo     = (const float*)d_in[11];
  const float* bo     = (const float*)d_in[12];
  const float* gate_w = (const float*)d_in[13];
  const float* gate_b = (const float*)d_in[14];
  const float* logit_scale = (const float*)d_in[15];
  const float* alpha  = (const float*)d_in[16];
  const float* ln2_w  = (const float*)d_in[17];
  const float* ln2_b  = (const float*)d_in[18];
  const float* ffn_w1 = (const float*)d_in[19];
  const float* ffn_b1 = (const float*)d_in[20];
  const float* ffn_w2 = (const float*)d_in[21];
  const float* ffn_b2 = (const float*)d_in[22];
  float* out = (float*)d_out;

  char* ws = (char*)d_ws;
  // R0 (88 MB): q fp32 -> SIM fp32 -> alignedO fp32 -> GCH bf16
  float* R0            = (float*)ws;
  float* BUF2          = (float*)(ws + 88080384);             // y fp32, 64 MB (step 8+)
  unsigned short* Xb   = (unsigned short*)(ws + 155189248);   // 32 MB
  unsigned short* QNb  = (unsigned short*)(ws + 188743680);   // 32 MB (-> ALb later)
  unsigned short* wqT  = (unsigned short*)(ws + 222298112);
  unsigned short* woT  = wqT + 262144;
  unsigned short* gateT = woT + 262144;
  unsigned short* w1T  = gateT + 262144;                      // [2048,512]
  unsigned short* w2T  = w1T + 1048576;                       // [512,2048]
  unsigned short* KHb  = w2T + 1048576;                       // [64,80,64] bf16
  float* NEGM = (float*)(ws + 230146048);                     // [8,80]
  float* CONF = (float*)(ws + 230148608);                     // [32768]

  // kv-projection scratch lives in the BUF2 region (dead until step 8):
  float* KV            = (float*)(ws + 88080384);             // [640,1024] fp32
  unsigned short* THi  = (unsigned short*)(ws + 88080384 + 2621440);   // [640,512]
  unsigned short* TLo  = THi + 640 * 512;
  unsigned short* WKVh = TLo + 640 * 512;                     // [1024,512]
  unsigned short* WKVl = WKVh + 1024 * 512;

  float* Qf = R0;
  float* SIM = R0;
  float* AO = R0;
  unsigned short* ALb = QNb;   // aliased: QN dead after sim_kernel

  // weight transposes -> bf16 [N,K]
  transpose_bf16_kernel<<<dim3(16, 16), 256, 0, stream>>>(wq, wqT, 512, 512);
  transpose_bf16_kernel<<<dim3(16, 16), 256, 0, stream>>>(wo, woT, 512, 512);
  transpose_bf16_kernel<<<dim3(16, 16), 256, 0, stream>>>(gate_w, gateT, 512, 512);
  transpose_bf16_kernel<<<dim3(64, 16), 256, 0, stream>>>(ffn_w1, w1T, 512, 2048);
  transpose_bf16_kernel<<<dim3(16, 64), 256, 0, stream>>>(ffn_w2, w2T, 2048, 512);
  // wk|wv -> hi/lo split transposed [1024,512]
  transpose_pair_kernel<<<dim3(16, 16), 256, 0, stream>>>(wk, WKVh, WKVl, 512, 512);
  transpose_pair_kernel<<<dim3(16, 16), 256, 0, stream>>>(wvw, WKVh + 512 * 512, WKVl + 512 * 512, 512, 512);

  // 1. x = LN1(visual) -> bf16
  ln_bf16_kernel<<<MTOT / 4, 256, 0, stream>>>(visual, ln1_w, ln1_b, Xb);
  // 2. text -> hi/lo bf16 + pad mask; kv = text @ (wk|wv) via split-bf16 MFMA
  text_cvt_kernel<<<160, 256, 0, stream>>>(text, THi, TLo, NEGM);
  kv_gemm<<<dim3(8, 5), 256, 0, stream>>>(THi, TLo, WKVh, WKVl, bk, bv, KV);
  knorm_kernel<<<154, 256, 0, stream>>>(KV, KHb);
  kpad_zero_kernel<<<48, 256, 0, stream>>>(KHb, NEGM);
  // 3. q = x @ wq + bq (fp32)
  mfma_gemm<0><<<dim3(4, 256), 256, 0, stream>>>(Xb, wqT, bq, Qf, MTOT, 512, 512,
                                                 nullptr, nullptr, nullptr, nullptr);
  // 4. qn = l2norm(q) * scale -> bf16
  qnorm_kernel<<<MTOT / 4, 256, 0, stream>>>(Qf, logit_scale, QNb);
  // 5. SIM = qn . k^T + negmask  (MFMA)   [overwrites Qf - dead]
  sim_kernel<<<dim3(32, 64), 256, 0, stream>>>(QNb, KHb, NEGM, SIM);
  // 6. lane-per-(row,head) topk/softmax/conf/PV -> ALb (bf16, overlays QNb), CONF
  attn_topk_pv_kernel<<<1024, 256, 0, stream>>>(SIM, KV + 512, ALb, CONF);
  // 7. alignedO = (aligned @ wo + bo) * conf -> AO fp32 (overlays SIM - dead)
  mfma_gemm<1><<<dim3(4, 256), 256, 0, stream>>>(ALb, woT, bo, AO, MTOT, 512, 512,
                                                 nullptr, CONF, nullptr, nullptr);
  // 8. y = x + alpha*sigmoid(x@gate_w+gate_b)*geo*alignedO -> BUF2 (KV dead now)
  mfma_gemm<2><<<dim3(4, 256), 256, 0, stream>>>(Xb, gateT, gate_b, BUF2, MTOT, 512, 512,
                                                 Xb, AO, geo, alpha);
  // 9. h = LN2(y) -> Xb (bf16)
  ln_bf16_kernel<<<MTOT / 4, 256, 0, stream>>>(BUF2, ln2_w, ln2_b, Xb);
  // 10. FFN in 2 chunks of 16384 rows; GCH (bf16) overlays R0 (AO dead)
  unsigned short* GCH = (unsigned short*)R0;
  for (int ch = 0; ch < 2; ++ch) {
    const size_t off = (size_t)ch * 16384;
    mfma_gemm<3><<<dim3(16, 128), 256, 0, stream>>>(Xb + off * 512, w1T, ffn_b1, GCH,
                                                    16384, 2048, 512,
                                                    nullptr, nullptr, nullptr, nullptr);
    mfma_gemm<4><<<dim3(4, 128), 256, 0, stream>>>(GCH, w2T, ffn_b2, out + off * 512,
                                                   16384, 512, 2048,
                                                   nullptr, BUF2 + off * 512, nullptr, nullptr);
  }
}

// Round 4
// 631.914 us; speedup vs baseline: 1.2711x; 1.0522x over previous
//
#include <hip/hip_runtime.h>
#include <hip/hip_bf16.h>
#include <math.h>

#define TT 77
#define MTOT 32768

typedef __attribute__((ext_vector_type(8))) short bf16x8;
typedef __attribute__((ext_vector_type(4))) float floatx4;

#define GPTR(p) ((const __attribute__((address_space(1))) void*)(p))
#define LPTR(p) ((__attribute__((address_space(3))) void*)(p))

__device__ __forceinline__ float wred_sum(float v) {
#pragma unroll
  for (int o = 32; o >= 1; o >>= 1) v += __shfl_xor(v, o, 64);
  return v;
}

__device__ __forceinline__ unsigned short f2bf(float f) {
  unsigned int u = __float_as_uint(f);
  unsigned int r = (u + 0x7fffu + ((u >> 16) & 1u)) >> 16;
  return (unsigned short)r;
}
__device__ __forceinline__ float bf2f(unsigned short h) {
  return __uint_as_float(((unsigned int)h) << 16);
}

// fast erf-based GELU: Abramowitz-Stegun 7.1.26, |err| <= 1.5e-7 (way below bf16 lsb)
__device__ __forceinline__ float fast_gelu(float o) {
  const float z = fabsf(o) * 0.70710678118654752f;
  const float t = __builtin_amdgcn_rcpf(fmaf(0.3275911f, z, 1.0f));
  float p = fmaf(1.061405429f, t, -1.453152027f);
  p = fmaf(p, t, 1.421413741f);
  p = fmaf(p, t, -0.284496736f);
  p = fmaf(p, t, 0.254829592f);
  p = p * t;
  const float erfz = fmaf(-p, __expf(-z * z), 1.0f);   // erf(|o|/sqrt2)
  const float s = __builtin_copysignf(erfz, o);
  return 0.5f * o * (1.0f + s);
}

__device__ __forceinline__ float fast_sigmoid(float o) {
  return __builtin_amdgcn_rcpf(1.0f + __expf(-o));
}

// ---------------- LayerNorm over rows of 512 -> bf16 out (one wave per row) ---
__global__ __launch_bounds__(256)
void ln_bf16_kernel(const float* __restrict__ in, const float* __restrict__ gw,
                    const float* __restrict__ gb, unsigned short* __restrict__ out) {
  const int wv = threadIdx.x >> 6, lane = threadIdx.x & 63;
  const size_t row = (size_t)blockIdx.x * 4 + wv;
  const float* p = in + row * 512 + lane * 8;
  float4 a = *(const float4*)p;
  float4 b = *(const float4*)(p + 4);
  float s = a.x + a.y + a.z + a.w + b.x + b.y + b.z + b.w;
  float mu = wred_sum(s) * (1.0f / 512.0f);
  float d[8] = {a.x - mu, a.y - mu, a.z - mu, a.w - mu,
                b.x - mu, b.y - mu, b.z - mu, b.w - mu};
  float ss = 0.f;
#pragma unroll
  for (int i = 0; i < 8; ++i) ss = fmaf(d[i], d[i], ss);
  float var = wred_sum(ss) * (1.0f / 512.0f);
  float rstd = rsqrtf(var + 1e-5f);
  float4 w0 = *(const float4*)(gw + lane * 8);
  float4 w1 = *(const float4*)(gw + lane * 8 + 4);
  float4 c0 = *(const float4*)(gb + lane * 8);
  float4 c1 = *(const float4*)(gb + lane * 8 + 4);
  float o[8];
  o[0] = d[0] * rstd * w0.x + c0.x;  o[1] = d[1] * rstd * w0.y + c0.y;
  o[2] = d[2] * rstd * w0.z + c0.z;  o[3] = d[3] * rstd * w0.w + c0.w;
  o[4] = d[4] * rstd * w1.x + c1.x;  o[5] = d[5] * rstd * w1.y + c1.y;
  o[6] = d[6] * rstd * w1.z + c1.z;  o[7] = d[7] * rstd * w1.w + c1.w;
  __align__(16) unsigned short ob[8];
#pragma unroll
  for (int i = 0; i < 8; ++i) ob[i] = f2bf(o[i]);
  *(uint4*)(out + row * 512 + lane * 8) = *(const uint4*)ob;
}

// ---------------- q row: L2-normalize + fold sim scale + bf16 ------------------
__global__ __launch_bounds__(256)
void qnorm_kernel(const float* __restrict__ q, const float* __restrict__ logit_scale,
                  unsigned short* __restrict__ qnb) {
  const int wv = threadIdx.x >> 6, lane = threadIdx.x & 63;
  const size_t row = (size_t)blockIdx.x * 4 + wv;
  const float ls = fminf(fmaxf(logit_scale[0], -2.0f), 2.0f);
  const float scale = expf(ls) * 0.125f;
  const float* p = q + row * 512 + lane * 8;
  float4 a = *(const float4*)p;
  float4 b = *(const float4*)(p + 4);
  float ss = a.x * a.x + a.y * a.y + a.z * a.z + a.w * a.w +
             b.x * b.x + b.y * b.y + b.z * b.z + b.w * b.w;
  ss = wred_sum(ss);
  const float nsc = scale / fmaxf(sqrtf(ss), 1e-6f);
  float o[8] = {a.x * nsc, a.y * nsc, a.z * nsc, a.w * nsc,
                b.x * nsc, b.y * nsc, b.z * nsc, b.w * nsc};
  __align__(16) unsigned short ob[8];
#pragma unroll
  for (int i = 0; i < 8; ++i) ob[i] = f2bf(o[i]);
  *(uint4*)(qnb + row * 512 + lane * 8) = *(const uint4*)ob;
}

// ---------------- weight transpose + bf16 convert: W[K,N] -> WT[N,K] ----------
__global__ __launch_bounds__(256)
void transpose_bf16_kernel(const float* __restrict__ W, unsigned short* __restrict__ WTb,
                           int K, int N) {
  __shared__ float s[32][33];
  const int tx = threadIdx.x & 31, ty = threadIdx.x >> 5;  // ty 0..7
  const int n0 = blockIdx.x * 32, k0 = blockIdx.y * 32;
#pragma unroll
  for (int j = 0; j < 4; ++j)
    s[ty + 8 * j][tx] = W[(size_t)(k0 + ty + 8 * j) * N + n0 + tx];
  __syncthreads();
#pragma unroll
  for (int j = 0; j < 4; ++j)
    WTb[(size_t)(n0 + ty + 8 * j) * K + k0 + tx] = f2bf(s[tx][ty + 8 * j]);
}

// ---------------- pair transpose: W[K,N] -> hi/lo split bf16 WT[N,K] ----------
__global__ __launch_bounds__(256)
void transpose_pair_kernel(const float* __restrict__ W,
                           unsigned short* __restrict__ WTh,
                           unsigned short* __restrict__ WTl, int K, int N) {
  __shared__ float s[32][33];
  const int tx = threadIdx.x & 31, ty = threadIdx.x >> 5;  // ty 0..7
  const int n0 = blockIdx.x * 32, k0 = blockIdx.y * 32;
#pragma unroll
  for (int j = 0; j < 4; ++j)
    s[ty + 8 * j][tx] = W[(size_t)(k0 + ty + 8 * j) * N + n0 + tx];
  __syncthreads();
#pragma unroll
  for (int j = 0; j < 4; ++j) {
    const float a = s[tx][ty + 8 * j];
    const unsigned short hi = f2bf(a);
    WTh[(size_t)(n0 + ty + 8 * j) * K + k0 + tx] = hi;
    WTl[(size_t)(n0 + ty + 8 * j) * K + k0 + tx] = f2bf(a - bf2f(hi));
  }
}

// ---------------- text -> hi/lo bf16 split (rows 616..639 zeroed) + pad mask --
__global__ __launch_bounds__(256)
void text_cvt_kernel(const float* __restrict__ text,
                     unsigned short* __restrict__ thi,
                     unsigned short* __restrict__ tlo,
                     float* __restrict__ negm) {
  const int wv = threadIdx.x >> 6, lane = threadIdx.x & 63;
  const int row = blockIdx.x * 4 + wv;       // 0..639
  if (row >= 616) {
    const uint4 z = {0u, 0u, 0u, 0u};
    *(uint4*)(thi + (size_t)row * 512 + lane * 8) = z;
    *(uint4*)(tlo + (size_t)row * 512 + lane * 8) = z;
    return;
  }
  const float* p = text + (size_t)row * 512 + lane * 8;
  float4 a = *(const float4*)p;
  float4 b = *(const float4*)(p + 4);
  float v[8] = {a.x, a.y, a.z, a.w, b.x, b.y, b.z, b.w};
  float ab = 0.f;
#pragma unroll
  for (int i = 0; i < 8; ++i) ab += fabsf(v[i]);
  ab = wred_sum(ab);
  __align__(16) unsigned short hb[8];
  __align__(16) unsigned short lb[8];
#pragma unroll
  for (int i = 0; i < 8; ++i) {
    hb[i] = f2bf(v[i]);
    lb[i] = f2bf(v[i] - bf2f(hb[i]));
  }
  *(uint4*)(thi + (size_t)row * 512 + lane * 8) = *(const uint4*)hb;
  *(uint4*)(tlo + (size_t)row * 512 + lane * 8) = *(const uint4*)lb;
  if (lane == 0) {
    const int bb = row / 77, t = row - bb * 77;
    negm[bb * 80 + t] = (ab <= 1e-6f) ? -INFINITY : 0.0f;
  }
}

// ---------------- kv projection GEMM, split-bf16 (~fp32 exact) ----------------
// out[640,1024] = (THi+TLo)[640,512] @ (WTh+WTl)[1024,512]^T + bias
// acc = AH*BH + AH*BL + AL*BH  (AL*BL term ~2^-18, dropped)
__global__ __launch_bounds__(256)
void kv_gemm(const unsigned short* __restrict__ AH,
             const unsigned short* __restrict__ AL,
             const unsigned short* __restrict__ BH,
             const unsigned short* __restrict__ BL,
             const float* __restrict__ bk, const float* __restrict__ bv,
             float* __restrict__ outp) {
  const int K = 512;
  __shared__ __align__(16) unsigned short AsH[128 * 32];
  __shared__ __align__(16) unsigned short AsL[128 * 32];
  __shared__ __align__(16) unsigned short BsH[128 * 32];
  __shared__ __align__(16) unsigned short BsL[128 * 32];
  const int tid = threadIdx.x;
  const int wid = tid >> 6, lane = tid & 63;
  const int wr = wid >> 1, wc = wid & 1;
  const int m16 = lane & 15, quad = lane >> 4;
  const int row0 = blockIdx.y * 128, col0 = blockIdx.x * 128;

  const floatx4 zero4 = {0.f, 0.f, 0.f, 0.f};
  floatx4 acc[4][4];
#pragma unroll
  for (int i = 0; i < 4; ++i)
#pragma unroll
    for (int j = 0; j < 4; ++j) acc[i][j] = zero4;

  const int srow = tid >> 2;
  const int schunk = (tid & 3) ^ (srow & 3);
  const unsigned short* AgH = AH + (size_t)(row0 + srow) * K + schunk * 8;
  const unsigned short* AgL = AL + (size_t)(row0 + srow) * K + schunk * 8;
  const unsigned short* BgH = BH + (size_t)(col0 + srow) * K + schunk * 8;
  const unsigned short* BgL = BL + (size_t)(col0 + srow) * K + schunk * 8;
  char* AsHB = (char*)AsH + tid * 16;
  char* AsLB = (char*)AsL + tid * 16;
  char* BsHB = (char*)BsH + tid * 16;
  char* BsLB = (char*)BsL + tid * 16;
  const int rq = quad ^ (m16 & 3);
  const int aOfs = (wr * 64 + m16) * 32 + rq * 8;
  const int bOfs = (wc * 64 + m16) * 32 + rq * 8;

  for (int k0 = 0; k0 < K; k0 += 32) {
    __syncthreads();
    __builtin_amdgcn_global_load_lds(GPTR(AgH + k0), LPTR(AsHB), 16, 0, 0);
    __builtin_amdgcn_global_load_lds(GPTR(AgH + (size_t)64 * K + k0), LPTR(AsHB + 4096), 16, 0, 0);
    __builtin_amdgcn_global_load_lds(GPTR(AgL + k0), LPTR(AsLB), 16, 0, 0);
    __builtin_amdgcn_global_load_lds(GPTR(AgL + (size_t)64 * K + k0), LPTR(AsLB + 4096), 16, 0, 0);
    __builtin_amdgcn_global_load_lds(GPTR(BgH + k0), LPTR(BsHB), 16, 0, 0);
    __builtin_amdgcn_global_load_lds(GPTR(BgH + (size_t)64 * K + k0), LPTR(BsHB + 4096), 16, 0, 0);
    __builtin_amdgcn_global_load_lds(GPTR(BgL + k0), LPTR(BsLB), 16, 0, 0);
    __builtin_amdgcn_global_load_lds(GPTR(BgL + (size_t)64 * K + k0), LPTR(BsLB + 4096), 16, 0, 0);
    __syncthreads();
    bf16x8 afH[4], afL[4], bfH[4], bfL[4];
#pragma unroll
    for (int i = 0; i < 4; ++i) {
      afH[i] = *(const bf16x8*)(AsH + aOfs + i * 16 * 32);
      afL[i] = *(const bf16x8*)(AsL + aOfs + i * 16 * 32);
      bfH[i] = *(const bf16x8*)(BsH + bOfs + i * 16 * 32);
      bfL[i] = *(const bf16x8*)(BsL + bOfs + i * 16 * 32);
    }
#pragma unroll
    for (int mi = 0; mi < 4; ++mi)
#pragma unroll
      for (int ni = 0; ni < 4; ++ni) {
        acc[mi][ni] = __builtin_amdgcn_mfma_f32_16x16x32_bf16(afH[mi], bfH[ni], acc[mi][ni], 0, 0, 0);
        acc[mi][ni] = __builtin_amdgcn_mfma_f32_16x16x32_bf16(afH[mi], bfL[ni], acc[mi][ni], 0, 0, 0);
        acc[mi][ni] = __builtin_amdgcn_mfma_f32_16x16x32_bf16(afL[mi], bfH[ni], acc[mi][ni], 0, 0, 0);
      }
  }

  const float* bp = (col0 < 512) ? bk : bv;
  const int cbase = (col0 < 512) ? col0 : col0 - 512;
  float bb[4];
#pragma unroll
  for (int ni = 0; ni < 4; ++ni) bb[ni] = bp[cbase + wc * 64 + ni * 16 + m16];
#pragma unroll
  for (int mi = 0; mi < 4; ++mi)
#pragma unroll
    for (int r = 0; r < 4; ++r) {
      const int row = row0 + wr * 64 + mi * 16 + quad * 4 + r;
#pragma unroll
      for (int ni = 0; ni < 4; ++ni) {
        const int col = col0 + wc * 64 + ni * 16 + m16;
        outp[(size_t)row * 1024 + col] = acc[mi][ni][r] + bb[ni];
      }
    }
}

// ---------------- k rows: L2-normalize -> head-major bf16 ---------------------
__global__ __launch_bounds__(256)
void knorm_kernel(const float* __restrict__ KV,     // [640,1024], k = cols 0..511
                  unsigned short* __restrict__ khb) {  // [B,8,80,64]
  const int wv = threadIdx.x >> 6, lane = threadIdx.x & 63;
  const int row = blockIdx.x * 4 + wv;   // 0..615
  const float* p = KV + (size_t)row * 1024 + lane * 8;
  float4 a = *(const float4*)p;
  float4 b = *(const float4*)(p + 4);
  float v[8] = {a.x, a.y, a.z, a.w, b.x, b.y, b.z, b.w};
  float ss = 0.f;
#pragma unroll
  for (int i = 0; i < 8; ++i) ss = fmaf(v[i], v[i], ss);
  ss = wred_sum(ss);
  const float sc = 1.0f / fmaxf(sqrtf(ss), 1e-6f);
  const int bb = row / 77, t = row - bb * 77;
  const int c = lane * 8, h = c >> 6, d = c & 63;
  __align__(16) unsigned short ob[8];
#pragma unroll
  for (int i = 0; i < 8; ++i) ob[i] = f2bf(v[i] * sc);
  *(uint4*)(khb + (((size_t)bb * 8 + h) * 80 + t) * 64 + d) = *(const uint4*)ob;
}

// ---------------- zero the k pad rows (t = 77..79) + -inf negmask there -------
__global__ __launch_bounds__(256)
void kpad_zero_kernel(unsigned short* __restrict__ khb, float* __restrict__ negm) {
  // 64 (b,h) * 3 rows * 64 ch = 12288 elements
  const int i = blockIdx.x * 256 + threadIdx.x;
  const int bh = i / 192, rem = i - bh * 192;
  const int t = 77 + rem / 64, d = rem & 63;
  khb[(((size_t)bh) * 80 + t) * 64 + d] = 0;
  if (i < 24) negm[(i / 3) * 80 + 77 + (i % 3)] = -INFINITY;
}

// ---------------- sims via MFMA: SIM[b,h,n,80] = qn . k^T + negmask -----------
__global__ __launch_bounds__(256)
void sim_kernel(const unsigned short* __restrict__ qnb,   // [32768,512] bf16 scaled
                const unsigned short* __restrict__ khb,   // [64,80,64] bf16
                const float* __restrict__ negm,           // [8,80]
                float* __restrict__ SIM) {                // [64,4096,80] fp32
  __shared__ __align__(16) unsigned short As[128 * 72];
  __shared__ __align__(16) unsigned short Bs[80 * 72];
  const int bh = blockIdx.y;           // b*8+h
  const int b = bh >> 3, h = bh & 7;
  const int row0 = blockIdx.x * 128;   // within 4096
  const int tid = threadIdx.x;
  // stage A: 128 rows x 64 bf16 (2 threads per row, 64B each)
  {
    const int r = tid >> 1, half = tid & 1;
    const unsigned short* src = qnb + ((size_t)b * 4096 + row0 + r) * 512 + h * 64 + half * 32;
    unsigned short* dst = As + r * 72 + half * 32;
    *(uint4*)dst = *(const uint4*)src;
    *(uint4*)(dst + 8) = *(const uint4*)(src + 8);
    *(uint4*)(dst + 16) = *(const uint4*)(src + 16);
    *(uint4*)(dst + 24) = *(const uint4*)(src + 24);
  }
  // stage B: 80 rows x 64 bf16
  if (tid < 160) {
    const int r = tid >> 1, half = tid & 1;
    const unsigned short* src = khb + ((size_t)bh * 80 + r) * 64 + half * 32;
    unsigned short* dst = Bs + r * 72 + half * 32;
    *(uint4*)dst = *(const uint4*)src;
    *(uint4*)(dst + 8) = *(const uint4*)(src + 8);
    *(uint4*)(dst + 16) = *(const uint4*)(src + 16);
    *(uint4*)(dst + 24) = *(const uint4*)(src + 24);
  }
  __syncthreads();
  const int w = tid >> 6, lane = tid & 63;
  const int m16 = lane & 15, quad = lane >> 4;
  const unsigned short* aBase = As + (w * 32 + m16) * 72 + quad * 8;
  const unsigned short* bBase = Bs + m16 * 72 + quad * 8;
  bf16x8 af[2][2], bf[5][2];
#pragma unroll
  for (int mi = 0; mi < 2; ++mi)
#pragma unroll
    for (int kk = 0; kk < 2; ++kk)
      af[mi][kk] = *(const bf16x8*)(aBase + mi * 16 * 72 + kk * 32);
#pragma unroll
  for (int ni = 0; ni < 5; ++ni)
#pragma unroll
    for (int kk = 0; kk < 2; ++kk)
      bf[ni][kk] = *(const bf16x8*)(bBase + ni * 16 * 72 + kk * 32);
  const floatx4 zero4 = {0.f, 0.f, 0.f, 0.f};
  floatx4 acc[2][5];
#pragma unroll
  for (int mi = 0; mi < 2; ++mi)
#pragma unroll
    for (int ni = 0; ni < 5; ++ni) acc[mi][ni] = zero4;
#pragma unroll
  for (int kk = 0; kk < 2; ++kk)
#pragma unroll
    for (int mi = 0; mi < 2; ++mi)
#pragma unroll
      for (int ni = 0; ni < 5; ++ni)
        acc[mi][ni] = __builtin_amdgcn_mfma_f32_16x16x32_bf16(af[mi][kk], bf[ni][kk], acc[mi][ni], 0, 0, 0);
  float nm[5];
#pragma unroll
  for (int ni = 0; ni < 5; ++ni) nm[ni] = negm[b * 80 + ni * 16 + m16];
  float* obase = SIM + ((size_t)bh * 4096 + row0 + w * 32 + quad * 4) * 80 + m16;
#pragma unroll
  for (int mi = 0; mi < 2; ++mi)
#pragma unroll
    for (int ni = 0; ni < 5; ++ni)
#pragma unroll
      for (int r = 0; r < 4; ++r)
        obase[(size_t)(mi * 16 + r) * 80 + ni * 16] = acc[mi][ni][r] + nm[ni];
}

// ---------------- lane-per-(row,head) top3 + closed-form softmax/conf + PV ----
// g = b*32768 + n*8 + h : the 8 heads of a row sit in adjacent lanes.
// vf points at KV+512 (v block), row stride 1024.
__global__ __launch_bounds__(256)
void attn_topk_pv_kernel(const float* __restrict__ SIM,         // [64,4096,80]
                         const float* __restrict__ vf,          // KV+512, stride 1024
                         unsigned short* __restrict__ alignedb, // [32768,512] bf16
                         float* __restrict__ conf_out) {        // [32768]
  const int g = blockIdx.x * 256 + threadIdx.x;
  const int b = g >> 15;
  const int local = g & 32767;
  const int n = local >> 3, h = local & 7;
  const float* sp = SIM + ((size_t)(b * 8 + h) * 4096 + n) * 80;

  // ---- streaming top-3 (with argmax) + m4 for boundary-tie detection ----
  float m1 = -INFINITY, m2 = -INFINITY, m3 = -INFINITY, m4 = -INFINITY;
  int a1 = 0, a2 = 0, a3 = 0;
#pragma unroll
  for (int i = 0; i < 20; ++i) {
    const float4 q = ((const float4*)sp)[i];
#pragma unroll
    for (int j = 0; j < 4; ++j) {
      const float v = (j == 0) ? q.x : (j == 1) ? q.y : (j == 2) ? q.z : q.w;
      const int t = i * 4 + j;
      const bool c1 = v > m1, c2 = v > m2, c3 = v > m3, c4 = v > m4;
      m4 = c4 ? (c3 ? m3 : v) : m4;            // uses old m3
      m3 = c3 ? (c2 ? m2 : v) : m3;            // uses old m2
      a3 = c3 ? (c2 ? a2 : t) : a3;
      m2 = c2 ? (c1 ? m1 : v) : m2;            // uses old m1
      a2 = c2 ? (c1 ? a1 : t) : a2;
      m1 = c1 ? v : m1;
      a1 = c1 ? t : a1;
    }
  }

  const bool dead = (m1 == -INFINITY);         // fully-padded row
  if (dead) m1 = 0.0f;
  // any duplicate inside top-3, or a 4th value tied with the threshold
  const bool tie = (!dead) && ((m1 == m2) || (m2 == m3) || (m3 == m4));

  // ---- closed-form softmax pieces (fast path: survivors = {a1,a2,a3}) ----
  const float d2 = m2 - m1, d3 = m3 - m1;      // <= 0 (or -inf)
  const float e2 = __expf(d2), e3 = __expf(d3);  // exp(-inf) = 0
  float s0 = 1.0f + e2 + e3;
  float s1 = ((e2 > 0.f) ? e2 * d2 : 0.f) + ((e3 > 0.f) ? e3 * d3 : 0.f);
  float cntf = 1.0f + ((e2 > 0.f) ? 1.f : 0.f) + ((e3 > 0.f) ? 1.f : 0.f);

  // ---- PV: 3 dense 64-ch FMAs against L2-resident V ----
  const float w1 = dead ? 0.f : 1.f;
  const float* v1p = vf + (size_t)(b * 77 + a1) * 1024 + h * 64;
  const float* v2p = vf + (size_t)(b * 77 + a2) * 1024 + h * 64;
  const float* v3p = vf + (size_t)(b * 77 + a3) * 1024 + h * 64;
  float4 acc[16];
#pragma unroll
  for (int i = 0; i < 16; ++i) {
    const float4 x1 = ((const float4*)v1p)[i];
    const float4 x2 = ((const float4*)v2p)[i];
    const float4 x3 = ((const float4*)v3p)[i];
    float4 r;
    r.x = fmaf(e3, x3.x, fmaf(e2, x2.x, w1 * x1.x));
    r.y = fmaf(e3, x3.y, fmaf(e2, x2.y, w1 * x1.y));
    r.z = fmaf(e3, x3.z, fmaf(e2, x2.z, w1 * x1.z));
    r.w = fmaf(e3, x3.w, fmaf(e2, x2.w, w1 * x1.w));
    acc[i] = r;
  }

  // ---- exact-tie slow path (never taken on continuous data) ----
  if (__any(tie)) {
    if (tie) {
      s0 = 0.f; s1 = 0.f; cntf = 0.f;
#pragma unroll
      for (int i = 0; i < 16; ++i) acc[i] = (float4){0.f, 0.f, 0.f, 0.f};
      for (int t = 0; t < 80; ++t) {
        const float v = sp[t];
        if (v >= m3) {
          const float e = expf(v - m1);
          if (e > 0.f) {
            s0 += e; s1 = fmaf(e, v - m1, s1); cntf += 1.f;
            const float4* vp = (const float4*)(vf + (size_t)(b * 77 + t) * 1024 + h * 64);
#pragma unroll
            for (int i = 0; i < 16; ++i) {
              const float4 x = vp[i];
              acc[i].x = fmaf(e, x.x, acc[i].x);
              acc[i].y = fmaf(e, x.y, acc[i].y);
              acc[i].z = fmaf(e, x.z, acc[i].z);
              acc[i].w = fmaf(e, x.w, acc[i].w);
            }
          }
        }
      }
    }
  }

  // ---- conf from closed form: -sum p log p = log(s0) - s1/s0 ----
  const float inv = 1.0f / s0;
  const float entn = (__logf(s0) - s1 * inv) + (77.0f - cntf) * 1.8420681e-7f;
  const float ent = fmaxf(entn / __logf(fmaxf(cntf, 2.0f)), 0.0f);
  float conf_h = fminf(fmaxf(inv * (1.0f - ent), 0.0f), 1.0f);
  if (dead) conf_h = 0.f;
  float cs = conf_h;
  cs += __shfl_xor(cs, 1, 64);
  cs += __shfl_xor(cs, 2, 64);
  cs += __shfl_xor(cs, 4, 64);
  if (h == 0) {
    const float cm = fminf(fmaxf(cs * 0.125f, 0.0f), 1.0f);
    conf_out[(size_t)b * 4096 + n] = 0.35f + 0.65f * cm;
  }

  // ---- store aligned (bf16, 128B contiguous per lane) ----
  unsigned short* op = alignedb + ((size_t)b * 4096 + n) * 512 + h * 64;
#pragma unroll
  for (int i = 0; i < 8; ++i) {
    const float4 lo = acc[2 * i], hi = acc[2 * i + 1];
    uint4 pk;
    pk.x = (unsigned int)f2bf(lo.x * inv) | ((unsigned int)f2bf(lo.y * inv) << 16);
    pk.y = (unsigned int)f2bf(lo.z * inv) | ((unsigned int)f2bf(lo.w * inv) << 16);
    pk.z = (unsigned int)f2bf(hi.x * inv) | ((unsigned int)f2bf(hi.y * inv) << 16);
    pk.w = (unsigned int)f2bf(hi.z * inv) | ((unsigned int)f2bf(hi.w * inv) << 16);
    *(uint4*)(op + i * 8) = pk;
  }
}

// ---------------- bf16 MFMA GEMM: out = epi(A[M,K] @ WT[N,K]^T + bias) --------
// LDS tiles use an in-row XOR swizzle (chunk ^= row&3) applied BOTH at the
// global source address (global_load_lds writes linearly) and at ds_read.
// Block ids are remapped with an XCD-chunked bijective swizzle (T1/m204) so
// col-blocks sharing an A row-panel land on the same XCD's L2.
// EPI: 0 fp32 out; 1 bf16 out * rowscale(e1f); 2 gate epilogue (al read as
// bf16 via e1f cast); 3 bf16 GELU out; 4 fp32 out + e1f residual.
template <int EPI>
__global__ __launch_bounds__(256)
void mfma_gemm(const unsigned short* __restrict__ A,
               const unsigned short* __restrict__ WT,
               const float* __restrict__ bias,
               void* __restrict__ outv, int M, int N, int K,
               const unsigned short* __restrict__ e0b,
               const float* __restrict__ e1f,
               const float* __restrict__ e2f,
               const float* __restrict__ scf) {
  __shared__ __align__(16) unsigned short As[128 * 32];
  __shared__ __align__(16) unsigned short Bs[128 * 32];
  const int tid = threadIdx.x;
  const int wid = tid >> 6, lane = tid & 63;
  const int wr = wid >> 1, wc = wid & 1;
  const int m16 = lane & 15, quad = lane >> 4;

  // XCD-chunked bijective block swizzle (hardware round-robins dispatch index
  // across 8 XCDs; give each XCD a contiguous chunk of x-fastest tile ids).
  const int nwg = gridDim.x * gridDim.y;
  const int orig = blockIdx.y * gridDim.x + blockIdx.x;
  const int qq = nwg >> 3, rr = nwg & 7;
  const int xcd = orig & 7, base = orig >> 3;
  const int logical = (xcd < rr ? xcd * (qq + 1) : rr * (qq + 1) + (xcd - rr) * qq) + base;
  const int bx = logical % gridDim.x, by = logical / gridDim.x;
  const int row0 = by * 128, col0 = bx * 128;

  const floatx4 zero4 = {0.f, 0.f, 0.f, 0.f};
  floatx4 acc[4][4];
#pragma unroll
  for (int i = 0; i < 4; ++i)
#pragma unroll
    for (int j = 0; j < 4; ++j) acc[i][j] = zero4;

  // staging: thread tid owns LDS row (tid>>2), chunk (tid&3); source chunk is
  // XOR-swizzled so the swizzled ds_read below sees the right data.
  const int srow = tid >> 2;
  const int schunk = (tid & 3) ^ (srow & 3);
  const unsigned short* Ag = A + (size_t)(row0 + srow) * K + schunk * 8;
  const unsigned short* Bg = WT + (size_t)(col0 + srow) * K + schunk * 8;
  char* AsB = (char*)As + tid * 16;
  char* BsB = (char*)Bs + tid * 16;
  const int rq = quad ^ (m16 & 3);   // swizzled read chunk (row&3 == m16&3)
  const unsigned short* aP = As + (wr * 64 + m16) * 32 + rq * 8;
  const unsigned short* bP = Bs + (wc * 64 + m16) * 32 + rq * 8;

  for (int k0 = 0; k0 < K; k0 += 32) {
    __syncthreads();
    __builtin_amdgcn_global_load_lds(GPTR(Ag + k0), LPTR(AsB), 16, 0, 0);
    __builtin_amdgcn_global_load_lds(GPTR(Ag + (size_t)64 * K + k0), LPTR(AsB + 4096), 16, 0, 0);
    __builtin_amdgcn_global_load_lds(GPTR(Bg + k0), LPTR(BsB), 16, 0, 0);
    __builtin_amdgcn_global_load_lds(GPTR(Bg + (size_t)64 * K + k0), LPTR(BsB + 4096), 16, 0, 0);
    __syncthreads();
    bf16x8 af[4], bfr[4];
#pragma unroll
    for (int i = 0; i < 4; ++i) {
      af[i] = *(const bf16x8*)(aP + i * 16 * 32);
      bfr[i] = *(const bf16x8*)(bP + i * 16 * 32);
    }
#pragma unroll
    for (int mi = 0; mi < 4; ++mi)
#pragma unroll
      for (int ni = 0; ni < 4; ++ni)
        acc[mi][ni] = __builtin_amdgcn_mfma_f32_16x16x32_bf16(af[mi], bfr[ni], acc[mi][ni], 0, 0, 0);
  }

  float* outf = (float*)outv;
  unsigned short* outb = (unsigned short*)outv;
  const unsigned short* albf = (const unsigned short*)e1f;   // EPI==2: bf16 AO
  float bb[4];
#pragma unroll
  for (int ni = 0; ni < 4; ++ni) bb[ni] = bias[col0 + wc * 64 + ni * 16 + m16];
  const float alphav = (EPI == 2) ? scf[0] : 0.f;

#pragma unroll
  for (int mi = 0; mi < 4; ++mi) {
#pragma unroll
    for (int r = 0; r < 4; ++r) {
      const int row = row0 + wr * 64 + mi * 16 + quad * 4 + r;
      float rowscale = 1.f, geo = 0.f;
      if (EPI == 1) rowscale = e1f[row];
      if (EPI == 2) geo = fminf(fmaxf(e2f[row], 0.3f), 1.0f);
#pragma unroll
      for (int ni = 0; ni < 4; ++ni) {
        const int col = col0 + wc * 64 + ni * 16 + m16;
        const size_t idx = (size_t)row * N + col;
        float o = acc[mi][ni][r] + bb[ni];
        if (EPI == 0) {
          outf[idx] = o;
        } else if (EPI == 1) {
          outb[idx] = f2bf(o * rowscale);
        } else if (EPI == 2) {
          const float x = bf2f(e0b[idx]);
          const float al = bf2f(albf[idx]);
          const float sg = fast_sigmoid(o);
          outf[idx] = x + alphav * sg * geo * al;
        } else if (EPI == 3) {
          outb[idx] = f2bf(fast_gelu(o));
        } else {
          outf[idx] = o + e1f[idx];
        }
      }
    }
  }
}

extern "C" void kernel_launch(void* const* d_in, const int* in_sizes, int n_in,
                              void* d_out, int out_size, void* d_ws, size_t ws_size,
                              hipStream_t stream) {
  const float* visual = (const float*)d_in[0];
  const float* text   = (const float*)d_in[1];
  const float* geo    = (const float*)d_in[2];
  const float* ln1_w  = (const float*)d_in[3];
  const float* ln1_b  = (const float*)d_in[4];
  const float* wq     = (const float*)d_in[5];
  const float* bq     = (const float*)d_in[6];
  const float* wk     = (const float*)d_in[7];
  const float* bk     = (const float*)d_in[8];
  const float* wvw    = (const float*)d_in[9];
  const float* bv     = (const float*)d_in[10];
  const float* wo     = (const float*)d_in[11];
  const float* bo     = (const float*)d_in[12];
  const float* gate_w = (const float*)d_in[13];
  const float* gate_b = (const float*)d_in[14];
  const float* logit_scale = (const float*)d_in[15];
  const float* alpha  = (const float*)d_in[16];
  const float* ln2_w  = (const float*)d_in[17];
  const float* ln2_b  = (const float*)d_in[18];
  const float* ffn_w1 = (const float*)d_in[19];
  const float* ffn_b1 = (const float*)d_in[20];
  const float* ffn_w2 = (const float*)d_in[21];
  const float* ffn_b2 = (const float*)d_in[22];
  float* out = (float*)d_out;

  char* ws = (char*)d_ws;
  // R0 (88 MB): q fp32 -> SIM fp32 -> AO bf16 -> GCH bf16
  float* R0            = (float*)ws;
  float* BUF2          = (float*)(ws + 88080384);             // y fp32, 64 MB (step 8+)
  unsigned short* Xb   = (unsigned short*)(ws + 155189248);   // 32 MB
  unsigned short* QNb  = (unsigned short*)(ws + 188743680);   // 32 MB (-> ALb later)
  unsigned short* wqT  = (unsigned short*)(ws + 222298112);
  unsigned short* woT  = wqT + 262144;
  unsigned short* gateT = woT + 262144;
  unsigned short* w1T  = gateT + 262144;                      // [2048,512]
  unsigned short* w2T  = w1T + 1048576;                       // [512,2048]
  unsigned short* KHb  = w2T + 1048576;                       // [64,80,64] bf16
  float* NEGM = (float*)(ws + 230146048);                     // [8,80]
  float* CONF = (float*)(ws + 230148608);                     // [32768]

  // kv-projection scratch lives in the BUF2 region (dead until step 8):
  float* KV            = (float*)(ws + 88080384);             // [640,1024] fp32
  unsigned short* THi  = (unsigned short*)(ws + 88080384 + 2621440);   // [640,512]
  unsigned short* TLo  = THi + 640 * 512;
  unsigned short* WKVh = TLo + 640 * 512;                     // [1024,512]
  unsigned short* WKVl = WKVh + 1024 * 512;

  float* Qf = R0;
  float* SIM = R0;
  unsigned short* AOb = (unsigned short*)R0;   // bf16 [32768,512], overlays SIM (dead)
  unsigned short* ALb = QNb;   // aliased: QN dead after sim_kernel

  // weight transposes -> bf16 [N,K]
  transpose_bf16_kernel<<<dim3(16, 16), 256, 0, stream>>>(wq, wqT, 512, 512);
  transpose_bf16_kernel<<<dim3(16, 16), 256, 0, stream>>>(wo, woT, 512, 512);
  transpose_bf16_kernel<<<dim3(16, 16), 256, 0, stream>>>(gate_w, gateT, 512, 512);
  transpose_bf16_kernel<<<dim3(64, 16), 256, 0, stream>>>(ffn_w1, w1T, 512, 2048);
  transpose_bf16_kernel<<<dim3(16, 64), 256, 0, stream>>>(ffn_w2, w2T, 2048, 512);
  // wk|wv -> hi/lo split transposed [1024,512]
  transpose_pair_kernel<<<dim3(16, 16), 256, 0, stream>>>(wk, WKVh, WKVl, 512, 512);
  transpose_pair_kernel<<<dim3(16, 16), 256, 0, stream>>>(wvw, WKVh + 512 * 512, WKVl + 512 * 512, 512, 512);

  // 1. x = LN1(visual) -> bf16
  ln_bf16_kernel<<<MTOT / 4, 256, 0, stream>>>(visual, ln1_w, ln1_b, Xb);
  // 2. text -> hi/lo bf16 + pad mask; kv = text @ (wk|wv) via split-bf16 MFMA
  text_cvt_kernel<<<160, 256, 0, stream>>>(text, THi, TLo, NEGM);
  kv_gemm<<<dim3(8, 5), 256, 0, stream>>>(THi, TLo, WKVh, WKVl, bk, bv, KV);
  knorm_kernel<<<154, 256, 0, stream>>>(KV, KHb);
  kpad_zero_kernel<<<48, 256, 0, stream>>>(KHb, NEGM);
  // 3. q = x @ wq + bq (fp32)
  mfma_gemm<0><<<dim3(4, 256), 256, 0, stream>>>(Xb, wqT, bq, Qf, MTOT, 512, 512,
                                                 nullptr, nullptr, nullptr, nullptr);
  // 4. qn = l2norm(q) * scale -> bf16
  qnorm_kernel<<<MTOT / 4, 256, 0, stream>>>(Qf, logit_scale, QNb);
  // 5. SIM = qn . k^T + negmask  (MFMA)   [overwrites Qf - dead]
  sim_kernel<<<dim3(32, 64), 256, 0, stream>>>(QNb, KHb, NEGM, SIM);
  // 6. lane-per-(row,head) topk/softmax/conf/PV -> ALb (bf16, overlays QNb), CONF
  attn_topk_pv_kernel<<<1024, 256, 0, stream>>>(SIM, KV + 512, ALb, CONF);
  // 7. alignedO = (aligned @ wo + bo) * conf -> AOb bf16 (overlays SIM - dead)
  mfma_gemm<1><<<dim3(4, 256), 256, 0, stream>>>(ALb, woT, bo, AOb, MTOT, 512, 512,
                                                 nullptr, CONF, nullptr, nullptr);
  // 8. y = x + alpha*sigmoid(x@gate_w+gate_b)*geo*alignedO -> BUF2 (KV dead now)
  mfma_gemm<2><<<dim3(4, 256), 256, 0, stream>>>(Xb, gateT, gate_b, BUF2, MTOT, 512, 512,
                                                 Xb, (const float*)AOb, geo, alpha);
  // 9. h = LN2(y) -> Xb (bf16)
  ln_bf16_kernel<<<MTOT / 4, 256, 0, stream>>>(BUF2, ln2_w, ln2_b, Xb);
  // 10. FFN in 2 chunks of 16384 rows; GCH (bf16) overlays R0 (AOb dead)
  unsigned short* GCH = (unsigned short*)R0;
  for (int ch = 0; ch < 2; ++ch) {
    const size_t off = (size_t)ch * 16384;
    mfma_gemm<3><<<dim3(16, 128), 256, 0, stream>>>(Xb + off * 512, w1T, ffn_b1, GCH,
                                                    16384, 2048, 512,
                                                    nullptr, nullptr, nullptr, nullptr);
    mfma_gemm<4><<<dim3(4, 128), 256, 0, stream>>>(GCH, w2T, ffn_b2, out + off * 512,
                                                   16384, 512, 2048,
                                                   nullptr, BUF2 + off * 512, nullptr, nullptr);
  }
}

// Round 5
// 606.236 us; speedup vs baseline: 1.3250x; 1.0424x over previous
//
#include <hip/hip_runtime.h>
#include <hip/hip_bf16.h>
#include <math.h>

#define TT 77
#define MTOT 32768

typedef __attribute__((ext_vector_type(8))) short bf16x8;
typedef __attribute__((ext_vector_type(4))) float floatx4;

#define GPTR(p) ((const __attribute__((address_space(1))) void*)(p))
#define LPTR(p) ((__attribute__((address_space(3))) void*)(p))

__device__ __forceinline__ float wred_sum(float v) {
#pragma unroll
  for (int o = 32; o >= 1; o >>= 1) v += __shfl_xor(v, o, 64);
  return v;
}

__device__ __forceinline__ unsigned short f2bf(float f) {
  unsigned int u = __float_as_uint(f);
  unsigned int r = (u + 0x7fffu + ((u >> 16) & 1u)) >> 16;
  return (unsigned short)r;
}
__device__ __forceinline__ float bf2f(unsigned short h) {
  return __uint_as_float(((unsigned int)h) << 16);
}
// hw packed RTNE f32->bf16 (bit-identical to f2bf), 2 values in 1 inst
__device__ __forceinline__ unsigned int cvt2bf(float a, float b) {
  unsigned int r;
  asm("v_cvt_pk_bf16_f32 %0, %1, %2" : "=v"(r) : "v"(a), "v"(b));
  return r;
}

// fast erf-based GELU: Abramowitz-Stegun 7.1.26, |err| <= 1.5e-7 (way below bf16 lsb)
__device__ __forceinline__ float fast_gelu(float o) {
  const float z = fabsf(o) * 0.70710678118654752f;
  const float t = __builtin_amdgcn_rcpf(fmaf(0.3275911f, z, 1.0f));
  float p = fmaf(1.061405429f, t, -1.453152027f);
  p = fmaf(p, t, 1.421413741f);
  p = fmaf(p, t, -0.284496736f);
  p = fmaf(p, t, 0.254829592f);
  p = p * t;
  const float erfz = fmaf(-p, __expf(-z * z), 1.0f);   // erf(|o|/sqrt2)
  const float s = __builtin_copysignf(erfz, o);
  return 0.5f * o * (1.0f + s);
}

__device__ __forceinline__ float fast_sigmoid(float o) {
  return __builtin_amdgcn_rcpf(1.0f + __expf(-o));
}

// ---------------- LayerNorm over rows of 512 -> bf16 out (one wave per row) ---
__global__ __launch_bounds__(256)
void ln_bf16_kernel(const float* __restrict__ in, const float* __restrict__ gw,
                    const float* __restrict__ gb, unsigned short* __restrict__ out) {
  const int wv = threadIdx.x >> 6, lane = threadIdx.x & 63;
  const size_t row = (size_t)blockIdx.x * 4 + wv;
  const float* p = in + row * 512 + lane * 8;
  float4 a = *(const float4*)p;
  float4 b = *(const float4*)(p + 4);
  float s = a.x + a.y + a.z + a.w + b.x + b.y + b.z + b.w;
  float mu = wred_sum(s) * (1.0f / 512.0f);
  float d[8] = {a.x - mu, a.y - mu, a.z - mu, a.w - mu,
                b.x - mu, b.y - mu, b.z - mu, b.w - mu};
  float ss = 0.f;
#pragma unroll
  for (int i = 0; i < 8; ++i) ss = fmaf(d[i], d[i], ss);
  float var = wred_sum(ss) * (1.0f / 512.0f);
  float rstd = rsqrtf(var + 1e-5f);
  float4 w0 = *(const float4*)(gw + lane * 8);
  float4 w1 = *(const float4*)(gw + lane * 8 + 4);
  float4 c0 = *(const float4*)(gb + lane * 8);
  float4 c1 = *(const float4*)(gb + lane * 8 + 4);
  float o[8];
  o[0] = d[0] * rstd * w0.x + c0.x;  o[1] = d[1] * rstd * w0.y + c0.y;
  o[2] = d[2] * rstd * w0.z + c0.z;  o[3] = d[3] * rstd * w0.w + c0.w;
  o[4] = d[4] * rstd * w1.x + c1.x;  o[5] = d[5] * rstd * w1.y + c1.y;
  o[6] = d[6] * rstd * w1.z + c1.z;  o[7] = d[7] * rstd * w1.w + c1.w;
  __align__(16) unsigned short ob[8];
#pragma unroll
  for (int i = 0; i < 8; ++i) ob[i] = f2bf(o[i]);
  *(uint4*)(out + row * 512 + lane * 8) = *(const uint4*)ob;
}

// ---------------- zero the per-row ||q||^2 accumulator ------------------------
__global__ __launch_bounds__(256)
void zero_ss_kernel(float* __restrict__ ssq) {
  ssq[blockIdx.x * 256 + threadIdx.x] = 0.0f;
}

// ---------------- weight transpose + bf16 convert: W[K,N] -> WT[N,K] ----------
__global__ __launch_bounds__(256)
void transpose_bf16_kernel(const float* __restrict__ W, unsigned short* __restrict__ WTb,
                           int K, int N) {
  __shared__ float s[32][33];
  const int tx = threadIdx.x & 31, ty = threadIdx.x >> 5;  // ty 0..7
  const int n0 = blockIdx.x * 32, k0 = blockIdx.y * 32;
#pragma unroll
  for (int j = 0; j < 4; ++j)
    s[ty + 8 * j][tx] = W[(size_t)(k0 + ty + 8 * j) * N + n0 + tx];
  __syncthreads();
#pragma unroll
  for (int j = 0; j < 4; ++j)
    WTb[(size_t)(n0 + ty + 8 * j) * K + k0 + tx] = f2bf(s[tx][ty + 8 * j]);
}

// ---------------- pair transpose: W[K,N] -> hi/lo split bf16 WT[N,K] ----------
__global__ __launch_bounds__(256)
void transpose_pair_kernel(const float* __restrict__ W,
                           unsigned short* __restrict__ WTh,
                           unsigned short* __restrict__ WTl, int K, int N) {
  __shared__ float s[32][33];
  const int tx = threadIdx.x & 31, ty = threadIdx.x >> 5;  // ty 0..7
  const int n0 = blockIdx.x * 32, k0 = blockIdx.y * 32;
#pragma unroll
  for (int j = 0; j < 4; ++j)
    s[ty + 8 * j][tx] = W[(size_t)(k0 + ty + 8 * j) * N + n0 + tx];
  __syncthreads();
#pragma unroll
  for (int j = 0; j < 4; ++j) {
    const float a = s[tx][ty + 8 * j];
    const unsigned short hi = f2bf(a);
    WTh[(size_t)(n0 + ty + 8 * j) * K + k0 + tx] = hi;
    WTl[(size_t)(n0 + ty + 8 * j) * K + k0 + tx] = f2bf(a - bf2f(hi));
  }
}

// ---------------- text -> hi/lo bf16 split (rows 616..639 zeroed) + pad mask --
__global__ __launch_bounds__(256)
void text_cvt_kernel(const float* __restrict__ text,
                     unsigned short* __restrict__ thi,
                     unsigned short* __restrict__ tlo,
                     float* __restrict__ negm) {
  const int wv = threadIdx.x >> 6, lane = threadIdx.x & 63;
  const int row = blockIdx.x * 4 + wv;       // 0..639
  if (row >= 616) {
    const uint4 z = {0u, 0u, 0u, 0u};
    *(uint4*)(thi + (size_t)row * 512 + lane * 8) = z;
    *(uint4*)(tlo + (size_t)row * 512 + lane * 8) = z;
    return;
  }
  const float* p = text + (size_t)row * 512 + lane * 8;
  float4 a = *(const float4*)p;
  float4 b = *(const float4*)(p + 4);
  float v[8] = {a.x, a.y, a.z, a.w, b.x, b.y, b.z, b.w};
  float ab = 0.f;
#pragma unroll
  for (int i = 0; i < 8; ++i) ab += fabsf(v[i]);
  ab = wred_sum(ab);
  __align__(16) unsigned short hb[8];
  __align__(16) unsigned short lb[8];
#pragma unroll
  for (int i = 0; i < 8; ++i) {
    hb[i] = f2bf(v[i]);
    lb[i] = f2bf(v[i] - bf2f(hb[i]));
  }
  *(uint4*)(thi + (size_t)row * 512 + lane * 8) = *(const uint4*)hb;
  *(uint4*)(tlo + (size_t)row * 512 + lane * 8) = *(const uint4*)lb;
  if (lane == 0) {
    const int bb = row / 77, t = row - bb * 77;
    negm[bb * 80 + t] = (ab <= 1e-6f) ? -INFINITY : 0.0f;
  }
}

// ---------------- kv projection GEMM, split-bf16 (~fp32 exact) ----------------
__global__ __launch_bounds__(256)
void kv_gemm(const unsigned short* __restrict__ AH,
             const unsigned short* __restrict__ AL,
             const unsigned short* __restrict__ BH,
             const unsigned short* __restrict__ BL,
             const float* __restrict__ bk, const float* __restrict__ bv,
             float* __restrict__ outp) {
  const int K = 512;
  __shared__ __align__(16) unsigned short AsH[128 * 32];
  __shared__ __align__(16) unsigned short AsL[128 * 32];
  __shared__ __align__(16) unsigned short BsH[128 * 32];
  __shared__ __align__(16) unsigned short BsL[128 * 32];
  const int tid = threadIdx.x;
  const int wid = tid >> 6, lane = tid & 63;
  const int wr = wid >> 1, wc = wid & 1;
  const int m16 = lane & 15, quad = lane >> 4;
  const int row0 = blockIdx.y * 128, col0 = blockIdx.x * 128;

  const floatx4 zero4 = {0.f, 0.f, 0.f, 0.f};
  floatx4 acc[4][4];
#pragma unroll
  for (int i = 0; i < 4; ++i)
#pragma unroll
    for (int j = 0; j < 4; ++j) acc[i][j] = zero4;

  const int srow = tid >> 2;
  const int schunk = (tid & 3) ^ (srow & 3);
  const unsigned short* AgH = AH + (size_t)(row0 + srow) * K + schunk * 8;
  const unsigned short* AgL = AL + (size_t)(row0 + srow) * K + schunk * 8;
  const unsigned short* BgH = BH + (size_t)(col0 + srow) * K + schunk * 8;
  const unsigned short* BgL = BL + (size_t)(col0 + srow) * K + schunk * 8;
  char* AsHB = (char*)AsH + tid * 16;
  char* AsLB = (char*)AsL + tid * 16;
  char* BsHB = (char*)BsH + tid * 16;
  char* BsLB = (char*)BsL + tid * 16;
  const int rq = quad ^ (m16 & 3);
  const int aOfs = (wr * 64 + m16) * 32 + rq * 8;
  const int bOfs = (wc * 64 + m16) * 32 + rq * 8;

  for (int k0 = 0; k0 < K; k0 += 32) {
    __syncthreads();
    __builtin_amdgcn_global_load_lds(GPTR(AgH + k0), LPTR(AsHB), 16, 0, 0);
    __builtin_amdgcn_global_load_lds(GPTR(AgH + (size_t)64 * K + k0), LPTR(AsHB + 4096), 16, 0, 0);
    __builtin_amdgcn_global_load_lds(GPTR(AgL + k0), LPTR(AsLB), 16, 0, 0);
    __builtin_amdgcn_global_load_lds(GPTR(AgL + (size_t)64 * K + k0), LPTR(AsLB + 4096), 16, 0, 0);
    __builtin_amdgcn_global_load_lds(GPTR(BgH + k0), LPTR(BsHB), 16, 0, 0);
    __builtin_amdgcn_global_load_lds(GPTR(BgH + (size_t)64 * K + k0), LPTR(BsHB + 4096), 16, 0, 0);
    __builtin_amdgcn_global_load_lds(GPTR(BgL + k0), LPTR(BsLB), 16, 0, 0);
    __builtin_amdgcn_global_load_lds(GPTR(BgL + (size_t)64 * K + k0), LPTR(BsLB + 4096), 16, 0, 0);
    __syncthreads();
    bf16x8 afH[4], afL[4], bfH[4], bfL[4];
#pragma unroll
    for (int i = 0; i < 4; ++i) {
      afH[i] = *(const bf16x8*)(AsH + aOfs + i * 16 * 32);
      afL[i] = *(const bf16x8*)(AsL + aOfs + i * 16 * 32);
      bfH[i] = *(const bf16x8*)(BsH + bOfs + i * 16 * 32);
      bfL[i] = *(const bf16x8*)(BsL + bOfs + i * 16 * 32);
    }
#pragma unroll
    for (int mi = 0; mi < 4; ++mi)
#pragma unroll
      for (int ni = 0; ni < 4; ++ni) {
        acc[mi][ni] = __builtin_amdgcn_mfma_f32_16x16x32_bf16(afH[mi], bfH[ni], acc[mi][ni], 0, 0, 0);
        acc[mi][ni] = __builtin_amdgcn_mfma_f32_16x16x32_bf16(afH[mi], bfL[ni], acc[mi][ni], 0, 0, 0);
        acc[mi][ni] = __builtin_amdgcn_mfma_f32_16x16x32_bf16(afL[mi], bfH[ni], acc[mi][ni], 0, 0, 0);
      }
  }

  const float* bp = (col0 < 512) ? bk : bv;
  const int cbase = (col0 < 512) ? col0 : col0 - 512;
  float bb[4];
#pragma unroll
  for (int ni = 0; ni < 4; ++ni) bb[ni] = bp[cbase + wc * 64 + ni * 16 + m16];
#pragma unroll
  for (int mi = 0; mi < 4; ++mi)
#pragma unroll
    for (int r = 0; r < 4; ++r) {
      const int row = row0 + wr * 64 + mi * 16 + quad * 4 + r;
#pragma unroll
      for (int ni = 0; ni < 4; ++ni) {
        const int col = col0 + wc * 64 + ni * 16 + m16;
        outp[(size_t)row * 1024 + col] = acc[mi][ni][r] + bb[ni];
      }
    }
}

// ---------------- k rows: L2-normalize -> head-major bf16 ---------------------
__global__ __launch_bounds__(256)
void knorm_kernel(const float* __restrict__ KV,     // [640,1024], k = cols 0..511
                  unsigned short* __restrict__ khb) {  // [B,8,80,64]
  const int wv = threadIdx.x >> 6, lane = threadIdx.x & 63;
  const int row = blockIdx.x * 4 + wv;   // 0..615
  const float* p = KV + (size_t)row * 1024 + lane * 8;
  float4 a = *(const float4*)p;
  float4 b = *(const float4*)(p + 4);
  float v[8] = {a.x, a.y, a.z, a.w, b.x, b.y, b.z, b.w};
  float ss = 0.f;
#pragma unroll
  for (int i = 0; i < 8; ++i) ss = fmaf(v[i], v[i], ss);
  ss = wred_sum(ss);
  const float sc = 1.0f / fmaxf(sqrtf(ss), 1e-6f);
  const int bb = row / 77, t = row - bb * 77;
  const int c = lane * 8, h = c >> 6, d = c & 63;
  __align__(16) unsigned short ob[8];
#pragma unroll
  for (int i = 0; i < 8; ++i) ob[i] = f2bf(v[i] * sc);
  *(uint4*)(khb + (((size_t)bb * 8 + h) * 80 + t) * 64 + d) = *(const uint4*)ob;
}

// ---------------- zero the k pad rows (t = 77..79) + -inf negmask there -------
__global__ __launch_bounds__(256)
void kpad_zero_kernel(unsigned short* __restrict__ khb, float* __restrict__ negm) {
  const int i = blockIdx.x * 256 + threadIdx.x;
  const int bh = i / 192, rem = i - bh * 192;
  const int t = 77 + rem / 64, d = rem & 63;
  khb[(((size_t)bh) * 80 + t) * 64 + d] = 0;
  if (i < 24) negm[(i / 3) * 80 + 77 + (i % 3)] = -INFINITY;
}

// ---------------- sims via MFMA: SIM = (q.k^T)*rowscale + negmask -------------
// rowscale = exp(clip(logit_scale))/8 / max(||q_row||, 1e-6)  (from ssq atomics)
__global__ __launch_bounds__(256)
void sim_kernel(const unsigned short* __restrict__ qnb,   // [32768,512] bf16 q
                const unsigned short* __restrict__ khb,   // [64,80,64] bf16
                const float* __restrict__ negm,           // [8,80]
                const float* __restrict__ ssq,            // [32768] ||q||^2
                const float* __restrict__ logit_scale,
                float* __restrict__ SIM) {                // [64,4096,80] fp32
  __shared__ __align__(16) unsigned short As[128 * 72];
  __shared__ __align__(16) unsigned short Bs[80 * 72];
  const int bh = blockIdx.y;           // b*8+h
  const int b = bh >> 3, h = bh & 7;
  const int row0 = blockIdx.x * 128;   // within 4096
  const int tid = threadIdx.x;
  {
    const int r = tid >> 1, half = tid & 1;
    const unsigned short* src = qnb + ((size_t)b * 4096 + row0 + r) * 512 + h * 64 + half * 32;
    unsigned short* dst = As + r * 72 + half * 32;
    *(uint4*)dst = *(const uint4*)src;
    *(uint4*)(dst + 8) = *(const uint4*)(src + 8);
    *(uint4*)(dst + 16) = *(const uint4*)(src + 16);
    *(uint4*)(dst + 24) = *(const uint4*)(src + 24);
  }
  if (tid < 160) {
    const int r = tid >> 1, half = tid & 1;
    const unsigned short* src = khb + ((size_t)bh * 80 + r) * 64 + half * 32;
    unsigned short* dst = Bs + r * 72 + half * 32;
    *(uint4*)dst = *(const uint4*)src;
    *(uint4*)(dst + 8) = *(const uint4*)(src + 8);
    *(uint4*)(dst + 16) = *(const uint4*)(src + 16);
    *(uint4*)(dst + 24) = *(const uint4*)(src + 24);
  }
  __syncthreads();
  const int w = tid >> 6, lane = tid & 63;
  const int m16 = lane & 15, quad = lane >> 4;
  const unsigned short* aBase = As + (w * 32 + m16) * 72 + quad * 8;
  const unsigned short* bBase = Bs + m16 * 72 + quad * 8;
  bf16x8 af[2][2], bf[5][2];
#pragma unroll
  for (int mi = 0; mi < 2; ++mi)
#pragma unroll
    for (int kk = 0; kk < 2; ++kk)
      af[mi][kk] = *(const bf16x8*)(aBase + mi * 16 * 72 + kk * 32);
#pragma unroll
  for (int ni = 0; ni < 5; ++ni)
#pragma unroll
    for (int kk = 0; kk < 2; ++kk)
      bf[ni][kk] = *(const bf16x8*)(bBase + ni * 16 * 72 + kk * 32);
  const floatx4 zero4 = {0.f, 0.f, 0.f, 0.f};
  floatx4 acc[2][5];
#pragma unroll
  for (int mi = 0; mi < 2; ++mi)
#pragma unroll
    for (int ni = 0; ni < 5; ++ni) acc[mi][ni] = zero4;
#pragma unroll
  for (int kk = 0; kk < 2; ++kk)
#pragma unroll
    for (int mi = 0; mi < 2; ++mi)
#pragma unroll
      for (int ni = 0; ni < 5; ++ni)
        acc[mi][ni] = __builtin_amdgcn_mfma_f32_16x16x32_bf16(af[mi][kk], bf[ni][kk], acc[mi][ni], 0, 0, 0);
  const float ls = fminf(fmaxf(logit_scale[0], -2.0f), 2.0f);
  const float scale = expf(ls) * 0.125f;
  float nm[5];
#pragma unroll
  for (int ni = 0; ni < 5; ++ni) nm[ni] = negm[b * 80 + ni * 16 + m16];
  float* obase = SIM + ((size_t)bh * 4096 + row0 + w * 32 + quad * 4) * 80 + m16;
#pragma unroll
  for (int mi = 0; mi < 2; ++mi)
#pragma unroll
    for (int r = 0; r < 4; ++r) {
      const int rl = row0 + w * 32 + quad * 4 + mi * 16 + r;
      const float ssv = ssq[(size_t)b * 4096 + rl];
      const float nsc = scale / fmaxf(sqrtf(ssv), 1e-6f);
#pragma unroll
      for (int ni = 0; ni < 5; ++ni)
        obase[(size_t)(mi * 16 + r) * 80 + ni * 16] = acc[mi][ni][r] * nsc + nm[ni];
    }
}

// ---------------- lane-per-(row,head) top3 + closed-form softmax/conf + PV ----
__global__ __launch_bounds__(256)
void attn_topk_pv_kernel(const float* __restrict__ SIM,         // [64,4096,80]
                         const float* __restrict__ vf,          // KV+512, stride 1024
                         unsigned short* __restrict__ alignedb, // [32768,512] bf16
                         float* __restrict__ conf_out) {        // [32768]
  const int g = blockIdx.x * 256 + threadIdx.x;
  const int b = g >> 15;
  const int local = g & 32767;
  const int n = local >> 3, h = local & 7;
  const float* sp = SIM + ((size_t)(b * 8 + h) * 4096 + n) * 80;

  float m1 = -INFINITY, m2 = -INFINITY, m3 = -INFINITY, m4 = -INFINITY;
  int a1 = 0, a2 = 0, a3 = 0;
#pragma unroll
  for (int i = 0; i < 20; ++i) {
    const float4 q = ((const float4*)sp)[i];
#pragma unroll
    for (int j = 0; j < 4; ++j) {
      const float v = (j == 0) ? q.x : (j == 1) ? q.y : (j == 2) ? q.z : q.w;
      const int t = i * 4 + j;
      const bool c1 = v > m1, c2 = v > m2, c3 = v > m3, c4 = v > m4;
      m4 = c4 ? (c3 ? m3 : v) : m4;
      m3 = c3 ? (c2 ? m2 : v) : m3;
      a3 = c3 ? (c2 ? a2 : t) : a3;
      m2 = c2 ? (c1 ? m1 : v) : m2;
      a2 = c2 ? (c1 ? a1 : t) : a2;
      m1 = c1 ? v : m1;
      a1 = c1 ? t : a1;
    }
  }

  const bool dead = (m1 == -INFINITY);
  if (dead) m1 = 0.0f;
  const bool tie = (!dead) && ((m1 == m2) || (m2 == m3) || (m3 == m4));

  const float d2 = m2 - m1, d3 = m3 - m1;
  const float e2 = __expf(d2), e3 = __expf(d3);
  float s0 = 1.0f + e2 + e3;
  float s1 = ((e2 > 0.f) ? e2 * d2 : 0.f) + ((e3 > 0.f) ? e3 * d3 : 0.f);
  float cntf = 1.0f + ((e2 > 0.f) ? 1.f : 0.f) + ((e3 > 0.f) ? 1.f : 0.f);

  const float w1 = dead ? 0.f : 1.f;
  const float* v1p = vf + (size_t)(b * 77 + a1) * 1024 + h * 64;
  const float* v2p = vf + (size_t)(b * 77 + a2) * 1024 + h * 64;
  const float* v3p = vf + (size_t)(b * 77 + a3) * 1024 + h * 64;
  float4 acc[16];
#pragma unroll
  for (int i = 0; i < 16; ++i) {
    const float4 x1 = ((const float4*)v1p)[i];
    const float4 x2 = ((const float4*)v2p)[i];
    const float4 x3 = ((const float4*)v3p)[i];
    float4 r;
    r.x = fmaf(e3, x3.x, fmaf(e2, x2.x, w1 * x1.x));
    r.y = fmaf(e3, x3.y, fmaf(e2, x2.y, w1 * x1.y));
    r.z = fmaf(e3, x3.z, fmaf(e2, x2.z, w1 * x1.z));
    r.w = fmaf(e3, x3.w, fmaf(e2, x2.w, w1 * x1.w));
    acc[i] = r;
  }

  if (__any(tie)) {
    if (tie) {
      s0 = 0.f; s1 = 0.f; cntf = 0.f;
#pragma unroll
      for (int i = 0; i < 16; ++i) acc[i] = (float4){0.f, 0.f, 0.f, 0.f};
      for (int t = 0; t < 80; ++t) {
        const float v = sp[t];
        if (v >= m3) {
          const float e = expf(v - m1);
          if (e > 0.f) {
            s0 += e; s1 = fmaf(e, v - m1, s1); cntf += 1.f;
            const float4* vp = (const float4*)(vf + (size_t)(b * 77 + t) * 1024 + h * 64);
#pragma unroll
            for (int i = 0; i < 16; ++i) {
              const float4 x = vp[i];
              acc[i].x = fmaf(e, x.x, acc[i].x);
              acc[i].y = fmaf(e, x.y, acc[i].y);
              acc[i].z = fmaf(e, x.z, acc[i].z);
              acc[i].w = fmaf(e, x.w, acc[i].w);
            }
          }
        }
      }
    }
  }

  const float inv = 1.0f / s0;
  const float entn = (__logf(s0) - s1 * inv) + (77.0f - cntf) * 1.8420681e-7f;
  const float ent = fmaxf(entn / __logf(fmaxf(cntf, 2.0f)), 0.0f);
  float conf_h = fminf(fmaxf(inv * (1.0f - ent), 0.0f), 1.0f);
  if (dead) conf_h = 0.f;
  float cs = conf_h;
  cs += __shfl_xor(cs, 1, 64);
  cs += __shfl_xor(cs, 2, 64);
  cs += __shfl_xor(cs, 4, 64);
  if (h == 0) {
    const float cm = fminf(fmaxf(cs * 0.125f, 0.0f), 1.0f);
    conf_out[(size_t)b * 4096 + n] = 0.35f + 0.65f * cm;
  }

  unsigned short* op = alignedb + ((size_t)b * 4096 + n) * 512 + h * 64;
#pragma unroll
  for (int i = 0; i < 8; ++i) {
    const float4 lo = acc[2 * i], hi = acc[2 * i + 1];
    uint4 pk;
    pk.x = cvt2bf(lo.x * inv, lo.y * inv);
    pk.y = cvt2bf(lo.z * inv, lo.w * inv);
    pk.z = cvt2bf(hi.x * inv, hi.y * inv);
    pk.w = cvt2bf(hi.z * inv, hi.w * inv);
    *(uint4*)(op + i * 8) = pk;
  }
}

// ---------------- bf16 MFMA GEMM: out = epi(A[M,K] @ WT[N,K]^T + bias) --------
// EPI: 1 bf16 out*rowscale; 2 gate epilogue; 3 bf16 GELU; 4 fp32 + residual;
//      5 bf16 out + per-row sum-of-squares atomics (e1f = ss buffer).
template <int EPI, int KC>
__global__ __launch_bounds__(256)
void mfma_gemm(const unsigned short* __restrict__ A,
               const unsigned short* __restrict__ WT,
               const float* __restrict__ bias,
               void* __restrict__ outv, int M, int N,
               const unsigned short* __restrict__ e0b,
               const float* __restrict__ e1f,
               const float* __restrict__ e2f,
               const float* __restrict__ scf) {
  __shared__ __align__(16) unsigned short As[128 * 32];
  __shared__ __align__(16) unsigned short Bs[128 * 32];
  const int tid = threadIdx.x;
  const int wid = tid >> 6, lane = tid & 63;
  const int wr = wid >> 1, wc = wid & 1;
  const int m16 = lane & 15, quad = lane >> 4;

  // XCD-chunked bijective block swizzle
  const int nwg = gridDim.x * gridDim.y;
  const int orig = blockIdx.y * gridDim.x + blockIdx.x;
  const int qq = nwg >> 3, rr = nwg & 7;
  const int xcd = orig & 7, base = orig >> 3;
  const int logical = (xcd < rr ? xcd * (qq + 1) : rr * (qq + 1) + (xcd - rr) * qq) + base;
  const int bx = logical % gridDim.x, by = logical / gridDim.x;
  const int row0 = by * 128, col0 = bx * 128;

  const floatx4 zero4 = {0.f, 0.f, 0.f, 0.f};
  floatx4 acc[4][4];
#pragma unroll
  for (int i = 0; i < 4; ++i)
#pragma unroll
    for (int j = 0; j < 4; ++j) acc[i][j] = zero4;

  const int srow = tid >> 2;
  const int schunk = (tid & 3) ^ (srow & 3);
  const unsigned short* Ag = A + (size_t)(row0 + srow) * KC + schunk * 8;
  const unsigned short* Bg = WT + (size_t)(col0 + srow) * KC + schunk * 8;
  char* AsB = (char*)As + tid * 16;
  char* BsB = (char*)Bs + tid * 16;
  const int rq = quad ^ (m16 & 3);
  const unsigned short* aP = As + (wr * 64 + m16) * 32 + rq * 8;
  const unsigned short* bP = Bs + (wc * 64 + m16) * 32 + rq * 8;

  for (int k0 = 0; k0 < KC; k0 += 32) {
    __syncthreads();
    __builtin_amdgcn_global_load_lds(GPTR(Ag + k0), LPTR(AsB), 16, 0, 0);
    __builtin_amdgcn_global_load_lds(GPTR(Ag + (size_t)64 * KC + k0), LPTR(AsB + 4096), 16, 0, 0);
    __builtin_amdgcn_global_load_lds(GPTR(Bg + k0), LPTR(BsB), 16, 0, 0);
    __builtin_amdgcn_global_load_lds(GPTR(Bg + (size_t)64 * KC + k0), LPTR(BsB + 4096), 16, 0, 0);
    __syncthreads();
    bf16x8 af[4], bfr[4];
#pragma unroll
    for (int i = 0; i < 4; ++i) {
      af[i] = *(const bf16x8*)(aP + i * 16 * 32);
      bfr[i] = *(const bf16x8*)(bP + i * 16 * 32);
    }
#pragma unroll
    for (int mi = 0; mi < 4; ++mi)
#pragma unroll
      for (int ni = 0; ni < 4; ++ni)
        acc[mi][ni] = __builtin_amdgcn_mfma_f32_16x16x32_bf16(af[mi], bfr[ni], acc[mi][ni], 0, 0, 0);
  }

  float* outf = (float*)outv;
  unsigned short* outb = (unsigned short*)outv;
  const unsigned short* albf = (const unsigned short*)e1f;   // EPI==2: bf16 AO
  float bb[4];
#pragma unroll
  for (int ni = 0; ni < 4; ++ni) bb[ni] = bias[col0 + wc * 64 + ni * 16 + m16];
  const float alphav = (EPI == 2) ? scf[0] : 0.f;

#pragma unroll
  for (int mi = 0; mi < 4; ++mi) {
#pragma unroll
    for (int r = 0; r < 4; ++r) {
      const int row = row0 + wr * 64 + mi * 16 + quad * 4 + r;
      float o[4];
#pragma unroll
      for (int ni = 0; ni < 4; ++ni) o[ni] = acc[mi][ni][r] + bb[ni];
      const size_t basei = (size_t)row * N + col0 + wc * 64 + m16;

      if (EPI == 5) {
        const unsigned int p01 = cvt2bf(o[0], o[1]);
        const unsigned int p23 = cvt2bf(o[2], o[3]);
        outb[basei] = (unsigned short)p01;
        outb[basei + 16] = (unsigned short)(p01 >> 16);
        outb[basei + 32] = (unsigned short)p23;
        outb[basei + 48] = (unsigned short)(p23 >> 16);
        float p = fmaf(o[0], o[0], fmaf(o[1], o[1], fmaf(o[2], o[2], o[3] * o[3])));
        p += __shfl_xor(p, 1, 64);
        p += __shfl_xor(p, 2, 64);
        p += __shfl_xor(p, 4, 64);
        p += __shfl_xor(p, 8, 64);
        if (m16 == 0) atomicAdd(const_cast<float*>(e1f) + row, p);
      } else if (EPI == 3) {
        const unsigned int p01 = cvt2bf(fast_gelu(o[0]), fast_gelu(o[1]));
        const unsigned int p23 = cvt2bf(fast_gelu(o[2]), fast_gelu(o[3]));
        outb[basei] = (unsigned short)p01;
        outb[basei + 16] = (unsigned short)(p01 >> 16);
        outb[basei + 32] = (unsigned short)p23;
        outb[basei + 48] = (unsigned short)(p23 >> 16);
      } else if (EPI == 1) {
        const float rowscale = e1f[row];
        const unsigned int p01 = cvt2bf(o[0] * rowscale, o[1] * rowscale);
        const unsigned int p23 = cvt2bf(o[2] * rowscale, o[3] * rowscale);
        outb[basei] = (unsigned short)p01;
        outb[basei + 16] = (unsigned short)(p01 >> 16);
        outb[basei + 32] = (unsigned short)p23;
        outb[basei + 48] = (unsigned short)(p23 >> 16);
      } else if (EPI == 2) {
        const float geo = fminf(fmaxf(e2f[row], 0.3f), 1.0f);
#pragma unroll
        for (int ni = 0; ni < 4; ++ni) {
          const size_t idx = basei + ni * 16;
          const float x = bf2f(e0b[idx]);
          const float al = bf2f(albf[idx]);
          const float sg = fast_sigmoid(o[ni]);
          outf[idx] = x + alphav * sg * geo * al;
        }
      } else {  // EPI == 4
#pragma unroll
        for (int ni = 0; ni < 4; ++ni) {
          const size_t idx = basei + ni * 16;
          outf[idx] = o[ni] + e1f[idx];
        }
      }
    }
  }
}

extern "C" void kernel_launch(void* const* d_in, const int* in_sizes, int n_in,
                              void* d_out, int out_size, void* d_ws, size_t ws_size,
                              hipStream_t stream) {
  const float* visual = (const float*)d_in[0];
  const float* text   = (const float*)d_in[1];
  const float* geo    = (const float*)d_in[2];
  const float* ln1_w  = (const float*)d_in[3];
  const float* ln1_b  = (const float*)d_in[4];
  const float* wq     = (const float*)d_in[5];
  const float* bq     = (const float*)d_in[6];
  const float* wk     = (const float*)d_in[7];
  const float* bk     = (const float*)d_in[8];
  const float* wvw    = (const float*)d_in[9];
  const float* bv     = (const float*)d_in[10];
  const float* wo     = (const float*)d_in[11];
  const float* bo     = (const float*)d_in[12];
  const float* gate_w = (const float*)d_in[13];
  const float* gate_b = (const float*)d_in[14];
  const float* logit_scale = (const float*)d_in[15];
  const float* alpha  = (const float*)d_in[16];
  const float* ln2_w  = (const float*)d_in[17];
  const float* ln2_b  = (const float*)d_in[18];
  const float* ffn_w1 = (const float*)d_in[19];
  const float* ffn_b1 = (const float*)d_in[20];
  const float* ffn_w2 = (const float*)d_in[21];
  const float* ffn_b2 = (const float*)d_in[22];
  float* out = (float*)d_out;

  char* ws = (char*)d_ws;
  float* R0            = (float*)ws;                          // SIM fp32 / GCH bf16
  float* BUF2          = (float*)(ws + 88080384);             // y fp32 (step 8+)
  unsigned short* Xb   = (unsigned short*)(ws + 155189248);   // 32 MB
  unsigned short* QNb  = (unsigned short*)(ws + 188743680);   // 32 MB (-> ALb later)
  unsigned short* wqT  = (unsigned short*)(ws + 222298112);
  unsigned short* woT  = wqT + 262144;
  unsigned short* gateT = woT + 262144;
  unsigned short* w1T  = gateT + 262144;                      // [2048,512]
  unsigned short* w2T  = w1T + 1048576;                       // [512,2048]
  unsigned short* KHb  = w2T + 1048576;                       // [64,80,64] bf16
  float* NEGM = (float*)(ws + 230146048);                     // [8,80]
  float* CONF = (float*)(ws + 230148608);                     // [32768]
  float* SSQ  = (float*)(ws + 230279680);                     // [32768] ||q||^2

  // kv-projection scratch lives in the BUF2 region (dead until step 8):
  float* KV            = (float*)(ws + 88080384);             // [640,1024] fp32
  unsigned short* THi  = (unsigned short*)(ws + 88080384 + 2621440);   // [640,512]
  unsigned short* TLo  = THi + 640 * 512;
  unsigned short* WKVh = TLo + 640 * 512;                     // [1024,512]
  unsigned short* WKVl = WKVh + 1024 * 512;

  float* SIM = R0;
  unsigned short* ALb = QNb;   // aliased: q dead after sim_kernel

  // weight transposes -> bf16 [N,K]
  transpose_bf16_kernel<<<dim3(16, 16), 256, 0, stream>>>(wq, wqT, 512, 512);
  transpose_bf16_kernel<<<dim3(16, 16), 256, 0, stream>>>(wo, woT, 512, 512);
  transpose_bf16_kernel<<<dim3(16, 16), 256, 0, stream>>>(gate_w, gateT, 512, 512);
  transpose_bf16_kernel<<<dim3(64, 16), 256, 0, stream>>>(ffn_w1, w1T, 512, 2048);
  transpose_bf16_kernel<<<dim3(16, 64), 256, 0, stream>>>(ffn_w2, w2T, 2048, 512);
  transpose_pair_kernel<<<dim3(16, 16), 256, 0, stream>>>(wk, WKVh, WKVl, 512, 512);
  transpose_pair_kernel<<<dim3(16, 16), 256, 0, stream>>>(wvw, WKVh + 512 * 512, WKVl + 512 * 512, 512, 512);

  // 1. x = LN1(visual) -> bf16 ; zero ss accumulator
  ln_bf16_kernel<<<MTOT / 4, 256, 0, stream>>>(visual, ln1_w, ln1_b, Xb);
  zero_ss_kernel<<<128, 256, 0, stream>>>(SSQ);
  // 2. text -> hi/lo bf16 + pad mask; kv = text @ (wk|wv) via split-bf16 MFMA
  text_cvt_kernel<<<160, 256, 0, stream>>>(text, THi, TLo, NEGM);
  kv_gemm<<<dim3(8, 5), 256, 0, stream>>>(THi, TLo, WKVh, WKVl, bk, bv, KV);
  knorm_kernel<<<154, 256, 0, stream>>>(KV, KHb);
  kpad_zero_kernel<<<48, 256, 0, stream>>>(KHb, NEGM);
  // 3. q = x @ wq + bq -> bf16 QNb + per-row ss atomics (fused l2norm, part 1)
  mfma_gemm<5, 512><<<dim3(4, 256), 256, 0, stream>>>(Xb, wqT, bq, QNb, MTOT, 512,
                                                      nullptr, SSQ, nullptr, nullptr);
  // 4. SIM = (q.k^T)*scale/||q|| + negmask  (fused l2norm, part 2)
  sim_kernel<<<dim3(32, 64), 256, 0, stream>>>(QNb, KHb, NEGM, SSQ, logit_scale, SIM);
  // 5. topk/softmax/conf/PV -> ALb (bf16, overlays QNb), CONF
  attn_topk_pv_kernel<<<1024, 256, 0, stream>>>(SIM, KV + 512, ALb, CONF);
  // 6. alignedO = (aligned @ wo + bo) * conf -> AOb bf16 (overlays SIM - dead)
  unsigned short* AOb = (unsigned short*)R0;
  mfma_gemm<1, 512><<<dim3(4, 256), 256, 0, stream>>>(ALb, woT, bo, AOb, MTOT, 512,
                                                      nullptr, CONF, nullptr, nullptr);
  // 7. y = x + alpha*sigmoid(x@gate_w+gate_b)*geo*alignedO -> BUF2 (KV dead now)
  mfma_gemm<2, 512><<<dim3(4, 256), 256, 0, stream>>>(Xb, gateT, gate_b, BUF2, MTOT, 512,
                                                      Xb, (const float*)AOb, geo, alpha);
  // 8. h = LN2(y) -> Xb (bf16)
  ln_bf16_kernel<<<MTOT / 4, 256, 0, stream>>>(BUF2, ln2_w, ln2_b, Xb);
  // 9. FFN in 2 chunks of 16384 rows; GCH (bf16) overlays R0 (AOb dead)
  unsigned short* GCH = (unsigned short*)R0;
  for (int ch = 0; ch < 2; ++ch) {
    const size_t off = (size_t)ch * 16384;
    mfma_gemm<3, 512><<<dim3(16, 128), 256, 0, stream>>>(Xb + off * 512, w1T, ffn_b1, GCH,
                                                         16384, 2048,
                                                         nullptr, nullptr, nullptr, nullptr);
    mfma_gemm<4, 2048><<<dim3(4, 128), 256, 0, stream>>>(GCH, w2T, ffn_b2, out + off * 512,
                                                         16384, 512,
                                                         nullptr, BUF2 + off * 512, nullptr, nullptr);
  }
}